// Round 1
// 1788.054 us; speedup vs baseline: 1.6254x; 1.6254x over previous
//
#include <hip/hip_runtime.h>
#include <math.h>

#define BN 16
#define NN 1024
#define DD 384
#define D2 768
#define C2 1536
#define NHEAD 8
#define DH 48

#define SZ_ND   (BN*NN*DD)      /* 6291456  */
#define SZ_N2D  (BN*NN*D2)      /* 12582912 */
#define SZ_NC2  (BN*NN*C2)      /* 25165824 */
#define SZ_QKV  (BN*NN*3*DD)    /* 18874368 */

typedef __bf16 bf16x8 __attribute__((ext_vector_type(8)));
typedef float f32x4v __attribute__((ext_vector_type(4)));
typedef unsigned short u16x4 __attribute__((ext_vector_type(4)));

__device__ __forceinline__ unsigned short f2bf(float x){
  unsigned int u = __float_as_uint(x);
  u += 0x7FFFu + ((u >> 16) & 1u);          // round-nearest-even to bf16
  return (unsigned short)(u >> 16);
}
__device__ __forceinline__ float bf2f(unsigned short h){
  return __uint_as_float(((unsigned int)h) << 16);
}

// ---------------- block reductions (256 threads = 4 waves) ----------------
__device__ __forceinline__ float blockReduceSum256(float v){
  __shared__ float red[4];
  #pragma unroll
  for (int o=32;o;o>>=1) v += __shfl_down(v,o,64);
  if ((threadIdx.x&63)==0) red[threadIdx.x>>6]=v;
  __syncthreads();
  float r = red[0]+red[1]+red[2]+red[3];
  __syncthreads();
  return r;
}
__device__ __forceinline__ float blockReduceMax256(float v){
  __shared__ float red[4];
  #pragma unroll
  for (int o=32;o;o>>=1) v = fmaxf(v, __shfl_down(v,o,64));
  if ((threadIdx.x&63)==0) red[threadIdx.x>>6]=v;
  __syncthreads();
  float r = fmaxf(fmaxf(red[0],red[1]),fmaxf(red[2],red[3]));
  __syncthreads();
  return r;
}

// ---------------- LayerNorm: one block per row ----------------
__global__ __launch_bounds__(256) void ln_kernel(const float* __restrict__ in,
    const float* __restrict__ g, const float* __restrict__ b,
    float* __restrict__ out, int C){
  const int row = blockIdx.x;
  const float* x = in + (size_t)row*C;
  float s=0.f;
  for (int i=threadIdx.x;i<C;i+=256) s += x[i];
  s = blockReduceSum256(s);
  const float mu = s / (float)C;
  float v=0.f;
  for (int i=threadIdx.x;i<C;i+=256){ float d = x[i]-mu; v += d*d; }
  v = blockReduceSum256(v);
  const float rs = rsqrtf(v/(float)C + 1e-5f);
  float* o = out + (size_t)row*C;
  for (int i=threadIdx.x;i<C;i+=256) o[i] = (x[i]-mu)*rs*g[i] + b[i];
}

// ---------------- row softmax (QS: softmax over channels d) ----------------
__global__ __launch_bounds__(256) void rowsoftmax_kernel(const float* __restrict__ in,
    float* __restrict__ out, int C){
  const int row = blockIdx.x;
  const float* x = in + (size_t)row*C;
  float m = -3.0e38f;
  for (int i=threadIdx.x;i<C;i+=256) m = fmaxf(m, x[i]);
  m = blockReduceMax256(m);
  float s = 0.f;
  for (int i=threadIdx.x;i<C;i+=256) s += expf(x[i]-m);
  s = blockReduceSum256(s);
  const float inv = 1.f/s;
  float* o = out + (size_t)row*C;
  for (int i=threadIdx.x;i<C;i+=256) o[i] = expf(x[i]-m)*inv;
}

// ---------------- column softmax over tokens n (KS) ----------------
__global__ __launch_bounds__(256) void colsoftmax_kernel(const float* __restrict__ in,
    float* __restrict__ out){
  const int dl = threadIdx.x & 63;
  const int nc = threadIdx.x >> 6;
  const int d  = blockIdx.x*64 + dl;
  const int b  = blockIdx.y;
  const float* p = in + (size_t)b*NN*DD + d;
  __shared__ float redm[4][64];
  __shared__ float reds[4][64];
  float m = -3.0e38f;
  for (int n=nc*256; n<nc*256+256; n++) m = fmaxf(m, p[(size_t)n*DD]);
  redm[nc][dl] = m; __syncthreads();
  m = fmaxf(fmaxf(redm[0][dl],redm[1][dl]),fmaxf(redm[2][dl],redm[3][dl]));
  float s=0.f;
  for (int n=nc*256;n<nc*256+256;n++) s += expf(p[(size_t)n*DD]-m);
  reds[nc][dl]=s; __syncthreads();
  s = reds[0][dl]+reds[1][dl]+reds[2][dl]+reds[3][dl];
  const float inv = 1.f/s;
  float* q = out + (size_t)b*NN*DD + d;
  for (int n=nc*256;n<nc*256+256;n++) q[(size_t)n*DD] = expf(p[(size_t)n*DD]-m)*inv;
}

// ---------------- channel attention core: one block per (b,h) ----------------
__global__ __launch_bounds__(256) void chattn_kernel(const float* __restrict__ qkv,
    const float* __restrict__ temp, float* __restrict__ co){
  const int b = blockIdx.x >> 3;
  const int h = blockIdx.x & 7;
  const int t = threadIdx.x;
  __shared__ float S[DH*DH];
  __shared__ float Qt[DH][33];
  __shared__ float Kt[DH][33];
  __shared__ float qn[DH], kn[DH];
  float accS[9];
  #pragma unroll
  for (int r=0;r<9;r++) accS[r]=0.f;
  if (t<DH){ qn[t]=0.f; kn[t]=0.f; }
  __syncthreads();
  const size_t base = (size_t)b*NN*3*DD + (size_t)h*DH;
  for (int n0=0;n0<NN;n0+=32){
    #pragma unroll
    for (int l=0;l<6;l++){
      int idx = l*256+t;
      int nl = idx/48, i = idx - nl*48;
      size_t a = base + (size_t)(n0+nl)*(3*DD) + i;
      Qt[i][nl] = qkv[a];
      Kt[i][nl] = qkv[a+DD];
    }
    __syncthreads();
    if (t<DH){
      float sq=0.f, sk=0.f;
      #pragma unroll
      for (int nl=0;nl<32;nl++){ float q=Qt[t][nl]; sq+=q*q; float k=Kt[t][nl]; sk+=k*k; }
      qn[t]+=sq; kn[t]+=sk;
    }
    #pragma unroll
    for (int r=0;r<9;r++){
      int e = r*256+t;
      int i = e/48, j = e - i*48;
      float s = accS[r];
      #pragma unroll 8
      for (int nl=0;nl<32;nl++) s += Qt[i][nl]*Kt[j][nl];
      accS[r] = s;
    }
    __syncthreads();
  }
  const float tp = temp[h];
  #pragma unroll
  for (int r=0;r<9;r++){
    int e = r*256+t;
    int i = e/48, j = e - i*48;
    float nq = fmaxf(sqrtf(qn[i]), 1e-12f);
    float nk = fmaxf(sqrtf(kn[j]), 1e-12f);
    S[e] = accS[r]*tp/(nq*nk);
  }
  __syncthreads();
  if (t<DH){
    float m=-3.0e38f;
    for (int j=0;j<DH;j++) m = fmaxf(m, S[t*DH+j]);
    float s=0.f;
    for (int j=0;j<DH;j++){ float e_ = expf(S[t*DH+j]-m); S[t*DH+j]=e_; s+=e_; }
    float inv = 1.f/s;
    for (int j=0;j<DH;j++) S[t*DH+j]*=inv;
  }
  __syncthreads();
  for (int n0=0;n0<NN;n0+=32){
    #pragma unroll
    for (int l=0;l<6;l++){
      int idx = l*256+t;
      int nl = idx/48, i = idx - nl*48;
      size_t a = base + (size_t)(n0+nl)*(3*DD) + i;
      Qt[i][nl] = qkv[a + 2*DD];   // V tile (reuse Qt)
    }
    __syncthreads();
    #pragma unroll
    for (int l=0;l<6;l++){
      int idx = l*256+t;
      int nl = idx/48, i = idx - nl*48;
      float s = 0.f;
      #pragma unroll 8
      for (int j=0;j<DH;j++) s += S[i*DH+j]*Qt[j][nl];
      co[ ((size_t)b*NN + n0+nl)*DD + (size_t)h*DH + i ] = s;
    }
    __syncthreads();
  }
}

// ---------------- tiled fp32 GEMM (kept for small batched GEMMs) ----------------
template<bool AT_, bool BT_, bool BIAS_, bool RES_>
__global__ __launch_bounds__(256) void gemm64_kernel(const float* __restrict__ A,
    const float* __restrict__ Bm, const float* __restrict__ bias,
    const float* __restrict__ res, float* __restrict__ Cc,
    int M, int Nd, int K, size_t sA, size_t sB, size_t sC)
{
  A  += (size_t)blockIdx.z*sA;
  Bm += (size_t)blockIdx.z*sB;
  Cc += (size_t)blockIdx.z*sC;
  const float* resp = RES_ ? res + (size_t)blockIdx.z*sC : nullptr;
  const int m0 = blockIdx.y*64, n0 = blockIdx.x*64;
  const int t = threadIdx.x, tx = t&15, ty = t>>4;
  __shared__ float As[16][68];
  __shared__ float Bs[16][68];
  float acc[4][4];
  #pragma unroll
  for (int i=0;i<4;i++)
    #pragma unroll
    for (int j=0;j<4;j++) acc[i][j]=0.f;

  for (int k0=0;k0<K;k0+=16){
    if (!AT_){
      const int r = t>>2, c4 = t&3;
      float4 av = *(const float4*)(A + (size_t)(m0+r)*K + k0 + c4*4);
      As[c4*4+0][r]=av.x; As[c4*4+1][r]=av.y; As[c4*4+2][r]=av.z; As[c4*4+3][r]=av.w;
    } else {
      const int r = t>>4, c4 = t&15;
      float4 av = *(const float4*)(A + (size_t)(k0+r)*M + m0 + c4*4);
      *(float4*)&As[r][c4*4] = av;
    }
    if (!BT_){
      const int r = t>>4, c4 = t&15;
      float4 bv = *(const float4*)(Bm + (size_t)(k0+r)*Nd + n0 + c4*4);
      *(float4*)&Bs[r][c4*4] = bv;
    } else {
      const int r = t>>2, c4 = t&3;
      float4 bv = *(const float4*)(Bm + (size_t)(n0+r)*K + k0 + c4*4);
      Bs[c4*4+0][r]=bv.x; Bs[c4*4+1][r]=bv.y; Bs[c4*4+2][r]=bv.z; Bs[c4*4+3][r]=bv.w;
    }
    __syncthreads();
    #pragma unroll
    for (int k=0;k<16;k++){
      const float4 a4 = *(const float4*)&As[k][ty*4];
      const float4 b4 = *(const float4*)&Bs[k][tx*4];
      float a_[4] = {a4.x,a4.y,a4.z,a4.w};
      float b_[4] = {b4.x,b4.y,b4.z,b4.w};
      #pragma unroll
      for (int i=0;i<4;i++)
        #pragma unroll
        for (int j=0;j<4;j++) acc[i][j] += a_[i]*b_[j];
    }
    __syncthreads();
  }
  float bv_[4];
  if (BIAS_){
    #pragma unroll
    for (int j=0;j<4;j++) bv_[j] = bias[n0 + tx*4 + j];
  }
  #pragma unroll
  for (int i=0;i<4;i++){
    const size_t row = (size_t)(m0 + ty*4 + i);
    float* Crow = Cc + row*Nd + n0 + tx*4;
    const float* Rrow = RES_ ? (resp + row*Nd + n0 + tx*4) : nullptr;
    #pragma unroll
    for (int j=0;j<4;j++){
      float v = acc[i][j];
      if (BIAS_) v += bv_[j];
      if (RES_)  v += Rrow[j];
      Crow[j] = v;
    }
  }
}

// ---------------- weight prep: transpose [K,N] -> bf16 hi/lo [N][K] ----------------
__global__ __launch_bounds__(256) void wconv_t_kernel(const float* __restrict__ in,
    unsigned short* __restrict__ oh, unsigned short* __restrict__ ol, int K, int N){
  __shared__ float tile[32][33];
  const int n0 = blockIdx.x*32, k0 = blockIdx.y*32;
  const int j = threadIdx.x & 31, i4 = threadIdx.x >> 5;
  #pragma unroll
  for (int s=0;s<4;s++){
    int i = i4*4+s;
    tile[i][j] = in[(size_t)(k0+i)*N + n0 + j];
  }
  __syncthreads();
  #pragma unroll
  for (int s=0;s<4;s++){
    int i = i4*4+s;
    float x = tile[j][i];                       // in[k0+j][n0+i]
    unsigned short h = f2bf(x);
    oh[(size_t)(n0+i)*K + k0 + j] = h;
    ol[(size_t)(n0+i)*K + k0 + j] = f2bf(x - bf2f(h));
  }
}

// ---------------- weight prep: convert-only (already [N,K]) ----------------
__global__ __launch_bounds__(256) void wconv_kernel(const float* __restrict__ in,
    unsigned short* __restrict__ oh, unsigned short* __restrict__ ol, int n){
  int i = blockIdx.x*256 + threadIdx.x;
  if (i < n){
    float x = in[i];
    unsigned short h = f2bf(x);
    oh[i] = h;
    ol[i] = f2bf(x - bf2f(h));
  }
}

// ---------------- bf16x3 split-precision MFMA GEMM ----------------
// C[M,N] = A[M,K](fp32) * B (bf16 hi/lo, pre-transposed [N][K]) (+bias)(+res)
// tile 128x128, BK=32, 4 waves (2x2), per-wave 4x4 frags of 16x16x32 MFMA.
// A hi/lo split in registers during staging; 3 MFMA per frag:
//   Ah*Bh + Al*Bh + Ah*Bl  (lo*lo term ~2^-18 rel, dropped)
template<bool BIAS_, bool RES_>
__global__ __launch_bounds__(256) void gemm_bf16x3_kernel(const float* __restrict__ A,
    const unsigned short* __restrict__ Bh, const unsigned short* __restrict__ Bl,
    const float* __restrict__ bias, const float* __restrict__ res,
    float* __restrict__ C, int M, int N, int K)
{
  const int t = threadIdx.x;
  const int m0 = blockIdx.y*128, n0 = blockIdx.x*128;
  // rows padded to 40 bf16 (80B = 5*16B): b128 frag reads 16B-aligned, ~2-way banks
  __shared__ unsigned short As_h[128][40];
  __shared__ unsigned short As_l[128][40];
  __shared__ unsigned short Bs_h[128][40];
  __shared__ unsigned short Bs_l[128][40];

  const float* Ab = A + (size_t)m0*K;
  const unsigned short* Bhb = Bh + (size_t)n0*K;
  const unsigned short* Blb = Bl + (size_t)n0*K;

  f32x4v acc[4][4];
  #pragma unroll
  for (int i=0;i<4;i++)
    #pragma unroll
    for (int j=0;j<4;j++) acc[i][j] = (f32x4v){0.f,0.f,0.f,0.f};

  const int w  = t >> 6;
  const int wm = w >> 1, wn = w & 1;          // 2x2 waves over 128x128
  const int lr = t & 15, g = (t & 63) >> 4;   // frag lane row/col, k-group
  const int ac = t & 7,  ar0 = t >> 3;        // A staging: k-chunk, row base
  const int brow = t >> 1, bc0 = (t & 1)*2;   // B staging

  for (int k0 = 0; k0 < K; k0 += 32){
    // ---- stage A 128x32 fp32 -> hi/lo bf16 ----
    #pragma unroll
    for (int p=0;p<4;p++){
      const int row = ar0 + p*32;
      const float4 v = *(const float4*)(Ab + (size_t)row*K + k0 + ac*4);
      const float xs[4] = {v.x, v.y, v.z, v.w};
      u16x4 hv, lv;
      #pragma unroll
      for (int j2=0;j2<4;j2++){
        unsigned short hh = f2bf(xs[j2]);
        hv[j2] = hh;
        lv[j2] = f2bf(xs[j2] - bf2f(hh));
      }
      *(u16x4*)&As_h[row][ac*4] = hv;
      *(u16x4*)&As_l[row][ac*4] = lv;
    }
    // ---- stage B 128x32 bf16 hi/lo (already [N][K]) ----
    #pragma unroll
    for (int c=0;c<2;c++){
      const int cc = bc0 + c;
      *(uint4*)&Bs_h[brow][cc*8] = *(const uint4*)(Bhb + (size_t)brow*K + k0 + cc*8);
      *(uint4*)&Bs_l[brow][cc*8] = *(const uint4*)(Blb + (size_t)brow*K + k0 + cc*8);
    }
    __syncthreads();

    // ---- fragments: lane lr = row/col (l&15), k = g*8 + 0..7 (m97-verified layout) ----
    bf16x8 ah[4], al[4], bhf[4], blf[4];
    #pragma unroll
    for (int i=0;i<4;i++){
      ah[i]  = *(const bf16x8*)&As_h[wm*64 + i*16 + lr][g*8];
      al[i]  = *(const bf16x8*)&As_l[wm*64 + i*16 + lr][g*8];
      bhf[i] = *(const bf16x8*)&Bs_h[wn*64 + i*16 + lr][g*8];
      blf[i] = *(const bf16x8*)&Bs_l[wn*64 + i*16 + lr][g*8];
    }
    #pragma unroll
    for (int mi=0;mi<4;mi++)
      #pragma unroll
      for (int ni=0;ni<4;ni++){
        f32x4v c_ = acc[mi][ni];
        c_ = __builtin_amdgcn_mfma_f32_16x16x32_bf16(ah[mi], bhf[ni], c_, 0,0,0);
        c_ = __builtin_amdgcn_mfma_f32_16x16x32_bf16(al[mi], bhf[ni], c_, 0,0,0);
        c_ = __builtin_amdgcn_mfma_f32_16x16x32_bf16(ah[mi], blf[ni], c_, 0,0,0);
        acc[mi][ni] = c_;
      }
    __syncthreads();
  }

  // ---- epilogue: C/D layout col=lane&15, row=(lane>>4)*4+reg (m89-verified) ----
  #pragma unroll
  for (int ni=0;ni<4;ni++){
    const int col = n0 + wn*64 + ni*16 + lr;
    const float bb = BIAS_ ? bias[col] : 0.f;
    #pragma unroll
    for (int mi=0;mi<4;mi++){
      const int r0 = m0 + wm*64 + mi*16 + g*4;
      #pragma unroll
      for (int r=0;r<4;r++){
        float v = acc[mi][ni][r] + bb;
        if (RES_) v += res[(size_t)(r0+r)*N + col];
        C[(size_t)(r0+r)*N + col] = v;
      }
    }
  }
}

// ---------------- LN(rep) + concat residual -> tx ----------------
__global__ __launch_bounds__(256) void ln_concat_kernel(const float* __restrict__ rep,
    const float* __restrict__ g, const float* __restrict__ b,
    const float* __restrict__ ch1, const float* __restrict__ ch2,
    float* __restrict__ tx){
  const int row = blockIdx.x;
  const float* x = rep + (size_t)row*D2;
  float s=0.f;
  for (int i=threadIdx.x;i<D2;i+=256) s += x[i];
  s = blockReduceSum256(s);
  const float mu = s / (float)D2;
  float v=0.f;
  for (int i=threadIdx.x;i<D2;i+=256){ float d = x[i]-mu; v += d*d; }
  v = blockReduceSum256(v);
  const float rs = rsqrtf(v/(float)D2 + 1e-5f);
  float* o = tx + (size_t)row*D2;
  for (int i=threadIdx.x;i<D2;i+=256){
    float val = (x[i]-mu)*rs*g[i] + b[i];
    float rv = (i<DD) ? ch1[(size_t)row*DD + i] : ch2[(size_t)row*DD + i - DD];
    o[i] = val + rv;
  }
}

// ---------------- depthwise 3x3 conv + bias + exact GELU ----------------
__global__ __launch_bounds__(256) void dwconv_gelu_kernel(const float* __restrict__ h1,
    const float* __restrict__ w, const float* __restrict__ bias, float* __restrict__ g){
  const int n = blockIdx.x & (NN-1);
  const int b = blockIdx.x >> 10;
  const int hh = n >> 5, ww = n & 31;
  const float* base = h1 + (size_t)b*NN*C2;
  for (int c = threadIdx.x; c < C2; c += 256){
    float acc = bias[c];
    const float* wc = w + (size_t)c*9;
    #pragma unroll
    for (int dh=-1;dh<=1;dh++){
      int h2 = hh+dh; if ((unsigned)h2 >= 32u) continue;
      #pragma unroll
      for (int dw=-1;dw<=1;dw++){
        int w2 = ww+dw; if ((unsigned)w2 >= 32u) continue;
        acc += base[(size_t)(h2*32+w2)*C2 + c] * wc[(dh+1)*3 + (dw+1)];
      }
    }
    float r = 0.5f*acc*(1.f + erff(acc*0.70710678118654752f));
    g[((size_t)b*NN + n)*C2 + c] = r;
  }
}

// ---------------- launch ----------------
extern "C" void kernel_launch(void* const* d_in, const int* in_sizes, int n_in,
                              void* d_out, int out_size, void* d_ws, size_t ws_size,
                              hipStream_t stream) {
  const float* x1     = (const float*)d_in[0];
  const float* x2     = (const float*)d_in[1];
  const float* ln1_g  = (const float*)d_in[2];
  const float* ln1_b  = (const float*)d_in[3];
  const float* qkv_w  = (const float*)d_in[4];
  const float* ca_temp= (const float*)d_in[5];
  const float* proj_w = (const float*)d_in[6];
  const float* proj_b = (const float*)d_in[7];
  const float* ln3_g  = (const float*)d_in[8];
  const float* ln3_b  = (const float*)d_in[9];
  const float* rp_w   = (const float*)d_in[10];
  const float* rp_b   = (const float*)d_in[11];
  const float* cn_g   = (const float*)d_in[12];
  const float* cn_b   = (const float*)d_in[13];
  const float* ln2_g  = (const float*)d_in[14];
  const float* ln2_b  = (const float*)d_in[15];
  const float* fc1_w  = (const float*)d_in[16];
  const float* fc1_b  = (const float*)d_in[17];
  const float* dw_w   = (const float*)d_in[18];
  const float* dw_b   = (const float*)d_in[19];
  const float* fc2_w  = (const float*)d_in[20];
  const float* fc2_b  = (const float*)d_in[21];
  float* out = (float*)d_out;
  float* W   = (float*)d_ws;

  // ---- workspace layout (peak 50,331,648 floats = 192 MiB, unchanged) ----
  // Phase A: yco [0,6.29M) ; qkvb [6.29M,25.17M) ; ch1 [25.17M,31.46M) ; ch2 [31.46M,37.75M)
  //          weights qkvwT/projwT at [37.75M, 38.34M)  (bf16 hi/lo, lazily converted)
  float* yco  = W;
  float* qkvb = W + (size_t)SZ_ND;
  float* ch1  = W + 25165824ull;
  float* ch2  = W + 31457280ull;
  unsigned short* qkvwT_h  = (unsigned short*)(W + 37748736ull);   // 1152*384
  unsigned short* qkvwT_l  = qkvwT_h + 442368u;
  unsigned short* projwT_h = qkvwT_l + 442368u;                    // 384*384
  unsigned short* projwT_l = projwT_h + 147456u;
  // Phase B aliases:
  float* n1  = W;
  float* n2  = W + (size_t)SZ_ND;
  float* KS  = W + 2ull*SZ_ND;
  float* QS  = W + 3ull*SZ_ND;
  float* ctx = W + (size_t)SZ_ND;           // over dead n2
  float* ATb = W;                            // over dead n1
  float* rep = W + (size_t)SZ_ND;            // over dead ctx/KS
  unsigned short* rpw_h = (unsigned short*)(W + 37748736ull);      // 768*384 (over dead qkvwT)
  unsigned short* rpw_l = rpw_h + 294912u;
  // Phase C aliases:
  float* txp  = out;
  float* h1   = W;                           // [0,25.17M)
  float* y2   = W + (size_t)SZ_NC2;          // [25.17M,37.75M)
  float* gbuf = W + (size_t)SZ_NC2;          // [25.17M,50.33M) after y2 dead
  unsigned short* fc1wT_h = (unsigned short*)(W + 37748736ull);    // 1536*768 (over dead rpw)
  unsigned short* fc1wT_l = fc1wT_h + 1179648u;
  unsigned short* fc2wT_h = (unsigned short*)W;                    // over dead h1 (post-dwconv)
  unsigned short* fc2wT_l = fc2wT_h + 1179648u;

  const int M = BN*NN;

  // ---- phase-A weight prep ----
  wconv_t_kernel<<<dim3(1152/32, DD/32), dim3(256), 0, stream>>>(qkv_w, qkvwT_h, qkvwT_l, DD, 1152);
  wconv_t_kernel<<<dim3(DD/32, DD/32), dim3(256), 0, stream>>>(proj_w, projwT_h, projwT_l, DD, DD);

  // ---- channel attention, stream 1 ----
  ln_kernel<<<dim3(M), dim3(256), 0, stream>>>(x1, ln1_g, ln1_b, yco, DD);
  gemm_bf16x3_kernel<false,false><<<dim3(1152/128, M/128), dim3(256), 0, stream>>>(
      yco, qkvwT_h, qkvwT_l, nullptr, nullptr, qkvb, M, 1152, DD);
  chattn_kernel<<<dim3(BN*NHEAD), dim3(256), 0, stream>>>(qkvb, ca_temp, yco);
  gemm_bf16x3_kernel<true,true><<<dim3(DD/128, M/128), dim3(256), 0, stream>>>(
      yco, projwT_h, projwT_l, proj_b, x1, ch1, M, DD, DD);

  // ---- channel attention, stream 2 ----
  ln_kernel<<<dim3(M), dim3(256), 0, stream>>>(x2, ln1_g, ln1_b, yco, DD);
  gemm_bf16x3_kernel<false,false><<<dim3(1152/128, M/128), dim3(256), 0, stream>>>(
      yco, qkvwT_h, qkvwT_l, nullptr, nullptr, qkvb, M, 1152, DD);
  chattn_kernel<<<dim3(BN*NHEAD), dim3(256), 0, stream>>>(qkvb, ca_temp, yco);
  gemm_bf16x3_kernel<true,true><<<dim3(DD/128, M/128), dim3(256), 0, stream>>>(
      yco, projwT_h, projwT_l, proj_b, x2, ch2, M, DD, DD);

  // ---- cross attention ----
  // rp_w is already [N,K]=[768,384]; convert (overwrites dead qkv/proj weight buffers)
  wconv_kernel<<<dim3(294912/256), dim3(256), 0, stream>>>(rp_w, rpw_h, rpw_l, 294912);
  ln_kernel<<<dim3(M), dim3(256), 0, stream>>>(ch1, ln3_g, ln3_b, n1, DD);
  ln_kernel<<<dim3(M), dim3(256), 0, stream>>>(ch2, ln3_g, ln3_b, n2, DD);
  rowsoftmax_kernel<<<dim3(M), dim3(256), 0, stream>>>(n2, QS, DD);
  colsoftmax_kernel<<<dim3(DD/64, BN), dim3(256), 0, stream>>>(n2, KS);
  // ctx[b] = KS_b^T [D,N] * n1_b [N,D] -> [D,D]   (n2 dead from here)
  gemm64_kernel<true,false,false,false><<<dim3(DD/64, DD/64, BN), dim3(256), 0, stream>>>(
      KS, n1, nullptr, nullptr, ctx, DD, DD, NN,
      (size_t)NN*DD, (size_t)NN*DD, (size_t)DD*DD);
  // ATb[b] = QS_b [N,D] * ctx_b [D,D] -> [N,D]    (n1 dead from here)
  gemm64_kernel<false,false,false,false><<<dim3(DD/64, NN/64, BN), dim3(256), 0, stream>>>(
      QS, ctx, nullptr, nullptr, ATb, NN, DD, DD,
      (size_t)NN*DD, (size_t)DD*DD, (size_t)NN*DD);
  // rep = ATb [M,D] * rp_w^T + rp_b -> [M,768]    (QS/ctx/KS dead from here)
  gemm_bf16x3_kernel<true,false><<<dim3(D2/128, M/128), dim3(256), 0, stream>>>(
      ATb, rpw_h, rpw_l, rp_b, nullptr, rep, M, D2, DD);
  // tx = concat(ch1,ch2) + LN(rep)
  ln_concat_kernel<<<dim3(M), dim3(256), 0, stream>>>(rep, cn_g, cn_b, ch1, ch2, txp);

  // ---- mix FFN ----
  wconv_t_kernel<<<dim3(C2/32, D2/32), dim3(256), 0, stream>>>(fc1_w, fc1wT_h, fc1wT_l, D2, C2);
  ln_kernel<<<dim3(M), dim3(256), 0, stream>>>(txp, ln2_g, ln2_b, y2, D2);
  gemm_bf16x3_kernel<true,false><<<dim3(C2/128, M/128), dim3(256), 0, stream>>>(
      y2, fc1wT_h, fc1wT_l, fc1_b, nullptr, h1, M, C2, D2);
  dwconv_gelu_kernel<<<dim3(M), dim3(256), 0, stream>>>(h1, dw_w, dw_b, gbuf);
  // fc2 weights converted into dead h1 region (after dwconv consumed h1)
  wconv_t_kernel<<<dim3(D2/32, C2/32), dim3(256), 0, stream>>>(fc2_w, fc2wT_h, fc2wT_l, C2, D2);
  gemm_bf16x3_kernel<true,true><<<dim3(D2/128, M/128), dim3(256), 0, stream>>>(
      gbuf, fc2wT_h, fc2wT_l, fc2_b, txp, out, M, D2, C2);
}

// Round 2
// 1388.367 us; speedup vs baseline: 2.0933x; 1.2879x over previous
//
#include <hip/hip_runtime.h>
#include <math.h>

#define BN 16
#define NN 1024
#define DD 384
#define D2 768
#define C2 1536
#define NHEAD 8
#define DH 48

#define SZ_ND   (BN*NN*DD)      /* 6291456  */
#define SZ_N2D  (BN*NN*D2)      /* 12582912 */
#define SZ_NC2  (BN*NN*C2)      /* 25165824 */
#define SZ_QKV  (BN*NN*3*DD)    /* 18874368 */

typedef __bf16 bf16x8 __attribute__((ext_vector_type(8)));
typedef float f32x4v __attribute__((ext_vector_type(4)));
typedef unsigned short u16x4 __attribute__((ext_vector_type(4)));

__device__ __forceinline__ unsigned short f2bf(float x){
  unsigned int u = __float_as_uint(x);
  u += 0x7FFFu + ((u >> 16) & 1u);          // round-nearest-even to bf16
  return (unsigned short)(u >> 16);
}
__device__ __forceinline__ float bf2f(unsigned short h){
  return __uint_as_float(((unsigned int)h) << 16);
}

// ---------------- block reductions (256 threads = 4 waves) ----------------
__device__ __forceinline__ float blockReduceSum256(float v){
  __shared__ float red[4];
  #pragma unroll
  for (int o=32;o;o>>=1) v += __shfl_down(v,o,64);
  if ((threadIdx.x&63)==0) red[threadIdx.x>>6]=v;
  __syncthreads();
  float r = red[0]+red[1]+red[2]+red[3];
  __syncthreads();
  return r;
}
__device__ __forceinline__ float blockReduceMax256(float v){
  __shared__ float red[4];
  #pragma unroll
  for (int o=32;o;o>>=1) v = fmaxf(v, __shfl_down(v,o,64));
  if ((threadIdx.x&63)==0) red[threadIdx.x>>6]=v;
  __syncthreads();
  float r = fmaxf(fmaxf(red[0],red[1]),fmaxf(red[2],red[3]));
  __syncthreads();
  return r;
}

// ---------------- LayerNorm: one block per row ----------------
__global__ __launch_bounds__(256) void ln_kernel(const float* __restrict__ in,
    const float* __restrict__ g, const float* __restrict__ b,
    float* __restrict__ out, int C){
  const int row = blockIdx.x;
  const float* x = in + (size_t)row*C;
  float s=0.f;
  for (int i=threadIdx.x;i<C;i+=256) s += x[i];
  s = blockReduceSum256(s);
  const float mu = s / (float)C;
  float v=0.f;
  for (int i=threadIdx.x;i<C;i+=256){ float d = x[i]-mu; v += d*d; }
  v = blockReduceSum256(v);
  const float rs = rsqrtf(v/(float)C + 1e-5f);
  float* o = out + (size_t)row*C;
  for (int i=threadIdx.x;i<C;i+=256) o[i] = (x[i]-mu)*rs*g[i] + b[i];
}

// ---------------- row softmax (QS: softmax over channels d) ----------------
__global__ __launch_bounds__(256) void rowsoftmax_kernel(const float* __restrict__ in,
    float* __restrict__ out, int C){
  const int row = blockIdx.x;
  const float* x = in + (size_t)row*C;
  float m = -3.0e38f;
  for (int i=threadIdx.x;i<C;i+=256) m = fmaxf(m, x[i]);
  m = blockReduceMax256(m);
  float s = 0.f;
  for (int i=threadIdx.x;i<C;i+=256) s += expf(x[i]-m);
  s = blockReduceSum256(s);
  const float inv = 1.f/s;
  float* o = out + (size_t)row*C;
  for (int i=threadIdx.x;i<C;i+=256) o[i] = expf(x[i]-m)*inv;
}

// ---------------- column softmax over tokens n (KS) ----------------
__global__ __launch_bounds__(256) void colsoftmax_kernel(const float* __restrict__ in,
    float* __restrict__ out){
  const int dl = threadIdx.x & 63;
  const int nc = threadIdx.x >> 6;
  const int d  = blockIdx.x*64 + dl;
  const int b  = blockIdx.y;
  const float* p = in + (size_t)b*NN*DD + d;
  __shared__ float redm[4][64];
  __shared__ float reds[4][64];
  float m = -3.0e38f;
  for (int n=nc*256; n<nc*256+256; n++) m = fmaxf(m, p[(size_t)n*DD]);
  redm[nc][dl] = m; __syncthreads();
  m = fmaxf(fmaxf(redm[0][dl],redm[1][dl]),fmaxf(redm[2][dl],redm[3][dl]));
  float s=0.f;
  for (int n=nc*256;n<nc*256+256;n++) s += expf(p[(size_t)n*DD]-m);
  reds[nc][dl]=s; __syncthreads();
  s = reds[0][dl]+reds[1][dl]+reds[2][dl]+reds[3][dl];
  const float inv = 1.f/s;
  float* q = out + (size_t)b*NN*DD + d;
  for (int n=nc*256;n<nc*256+256;n++) q[(size_t)n*DD] = expf(p[(size_t)n*DD]-m)*inv;
}

// ---------------- channel attention, MFMA version: one block per (b,h) ----------------
// S = Qn*Kn^T (K-dim = N=1024) via 16x16x32 bf16x3 MFMA; wave 3 computes
// diag(Q*Q^T), diag(K*K^T) for the l2 norms. Softmax rows -> P (bf16 hi/lo,
// zero-padded to K=64). PV = P*V with 16x16x32 bf16x3, output float4 stores.
__global__ __launch_bounds__(256) void chattn_mfma_kernel(
    const float* __restrict__ qkv, const float* __restrict__ temp,
    float* __restrict__ co)
{
  const int bh = blockIdx.x, b = bh >> 3, h = bh & 7;
  const int t = threadIdx.x, w = t >> 6, lane = t & 63;
  const int lr = lane & 15, g = lane >> 4;

  // union region: phase1 Q/K tiles [48][72] hi/lo; phase2 V tiles [64][72] hi/lo
  __shared__ __align__(16) unsigned char ldsA[27648];
  unsigned short (*Qh)[72] = (unsigned short(*)[72])(ldsA);
  unsigned short (*Ql)[72] = (unsigned short(*)[72])(ldsA + 6912);
  unsigned short (*Kh)[72] = (unsigned short(*)[72])(ldsA + 13824);
  unsigned short (*Kl)[72] = (unsigned short(*)[72])(ldsA + 20736);
  unsigned short (*Vh)[72] = (unsigned short(*)[72])(ldsA);
  unsigned short (*Vl)[72] = (unsigned short(*)[72])(ldsA + 9216);
  __shared__ unsigned short Ph[48][72], Pl[48][72];
  __shared__ float S[48][49];
  __shared__ float qn[48], kn[48];

  const size_t base = (size_t)b*NN*1152 + (size_t)h*48;

  // phase-1 staging assignments: 768 = Q(384) + K(384) pair-loads, 3 per thread
  int agrp[3], apr[3], aoff[3];
  #pragma unroll
  for (int l=0;l<3;l++){
    int idx = l*256+t;
    int mo = (idx>=384) ? 1 : 0;
    int a = idx - mo*384;
    agrp[l] = a%12; apr[l] = a/12; aoff[l] = mo*384;
  }

  f32x4v acc[12];
  #pragma unroll
  for (int i=0;i<12;i++) acc[i] = (f32x4v){0.f,0.f,0.f,0.f};

  float4 cur[3][2];
  #pragma unroll
  for (int l=0;l<3;l++){
    const float* p = qkv + base + (size_t)(apr[l]*2)*1152 + aoff[l] + agrp[l]*4;
    cur[l][0] = *(const float4*)p;
    cur[l][1] = *(const float4*)(p+1152);
  }

  for (int nc=0; nc<16; nc++){
    // convert + transposed store of current chunk (paired tokens -> b32 writes)
    #pragma unroll
    for (int l=0;l<3;l++){
      unsigned short (*Dh)[72] = aoff[l] ? Kh : Qh;
      unsigned short (*Dl)[72] = aoff[l] ? Kl : Ql;
      const float x0[4] = {cur[l][0].x, cur[l][0].y, cur[l][0].z, cur[l][0].w};
      const float x1[4] = {cur[l][1].x, cur[l][1].y, cur[l][1].z, cur[l][1].w};
      #pragma unroll
      for (int c=0;c<4;c++){
        int d = agrp[l]*4+c;
        unsigned short h0 = f2bf(x0[c]), h1 = f2bf(x1[c]);
        unsigned short l0 = f2bf(x0[c]-bf2f(h0)), l1 = f2bf(x1[c]-bf2f(h1));
        *(unsigned int*)&Dh[d][apr[l]*2] = (unsigned)h0 | ((unsigned)h1<<16);
        *(unsigned int*)&Dl[d][apr[l]*2] = (unsigned)l0 | ((unsigned)l1<<16);
      }
    }
    __syncthreads();
    if (nc < 15){   // prefetch next chunk (overlaps MFMA below)
      #pragma unroll
      for (int l=0;l<3;l++){
        const float* p = qkv + base + (size_t)((nc+1)*64 + apr[l]*2)*1152 + aoff[l] + agrp[l]*4;
        cur[l][0] = *(const float4*)p;
        cur[l][1] = *(const float4*)(p+1152);
      }
    }
    if (w < 3){
      #pragma unroll
      for (int ks=0;ks<2;ks++){
        bf16x8 a_h = *(const bf16x8*)&Qh[w*16+lr][ks*32+g*8];
        bf16x8 a_l = *(const bf16x8*)&Ql[w*16+lr][ks*32+g*8];
        #pragma unroll
        for (int c=0;c<3;c++){
          bf16x8 b_h = *(const bf16x8*)&Kh[c*16+lr][ks*32+g*8];
          bf16x8 b_l = *(const bf16x8*)&Kl[c*16+lr][ks*32+g*8];
          acc[c] = __builtin_amdgcn_mfma_f32_16x16x32_bf16(a_h, b_h, acc[c], 0,0,0);
          acc[c] = __builtin_amdgcn_mfma_f32_16x16x32_bf16(a_l, b_h, acc[c], 0,0,0);
          acc[c] = __builtin_amdgcn_mfma_f32_16x16x32_bf16(a_h, b_l, acc[c], 0,0,0);
        }
      }
    } else {
      // wave 3: norm accumulators diag(Q Q^T), diag(K K^T): h*h + h*l tiles
      #pragma unroll
      for (int ks=0;ks<2;ks++){
        #pragma unroll
        for (int c=0;c<3;c++){
          bf16x8 qh_ = *(const bf16x8*)&Qh[c*16+lr][ks*32+g*8];
          bf16x8 ql_ = *(const bf16x8*)&Ql[c*16+lr][ks*32+g*8];
          bf16x8 kh_ = *(const bf16x8*)&Kh[c*16+lr][ks*32+g*8];
          bf16x8 kl_ = *(const bf16x8*)&Kl[c*16+lr][ks*32+g*8];
          acc[c]   = __builtin_amdgcn_mfma_f32_16x16x32_bf16(qh_, qh_, acc[c],   0,0,0);
          acc[3+c] = __builtin_amdgcn_mfma_f32_16x16x32_bf16(qh_, ql_, acc[3+c], 0,0,0);
          acc[6+c] = __builtin_amdgcn_mfma_f32_16x16x32_bf16(kh_, kh_, acc[6+c], 0,0,0);
          acc[9+c] = __builtin_amdgcn_mfma_f32_16x16x32_bf16(kh_, kl_, acc[9+c], 0,0,0);
        }
      }
    }
    __syncthreads();
  }

  const float tp = temp[h];
  if (w == 3){
    // diag element p of a tile lives in lane ((p>>2)<<4)|p, reg p&3
    if ((lane>>4) == ((lane&15)>>2)){
      int p = lane & 15, r = p & 3;
      #pragma unroll
      for (int c=0;c<3;c++){
        float q2 = fmaxf(acc[c][r]   + 2.f*acc[3+c][r], 0.f);
        float k2 = fmaxf(acc[6+c][r] + 2.f*acc[9+c][r], 0.f);
        qn[c*16+p] = fmaxf(sqrtf(q2), 1e-12f);
        kn[c*16+p] = fmaxf(sqrtf(k2), 1e-12f);
      }
    }
  }
  __syncthreads();
  if (w < 3){
    #pragma unroll
    for (int c=0;c<3;c++){
      #pragma unroll
      for (int r=0;r<4;r++){
        int i = w*16 + g*4 + r, j = c*16 + lr;
        S[i][j] = acc[c][r]*tp/(qn[i]*kn[j]);
      }
    }
  }
  __syncthreads();

  // V staging assignments (768 loads = 3/thread) + prefetch chunk 0
  int vgrp[3], vtk[3];
  #pragma unroll
  for (int l=0;l<3;l++){ int idx=l*256+t; vtk[l]=idx/12; vgrp[l]=idx%12; }
  float4 pv[3];
  #pragma unroll
  for (int l=0;l<3;l++)
    pv[l] = *(const float4*)(qkv + base + (size_t)vtk[l]*1152 + 768 + vgrp[l]*4);

  // softmax rows (t<48) ; others zero the V pad columns (j=48..63)
  if (t < 48){
    float m = -3.0e38f;
    for (int j=0;j<48;j++) m = fmaxf(m, S[t][j]);
    float s = 0.f;
    for (int j=0;j<48;j++){ float e_ = expf(S[t][j]-m); S[t][j] = e_; s += e_; }
    float inv = 1.f/s;
    for (int j=0;j<48;j++){
      float p = S[t][j]*inv;
      unsigned short hp = f2bf(p);
      Ph[t][j] = hp; Pl[t][j] = f2bf(p - bf2f(hp));
    }
    #pragma unroll
    for (int j=48;j<64;j++){ Ph[t][j]=0; Pl[t][j]=0; }
  } else {
    const u16x4 z4 = (u16x4){0,0,0,0};
    for (int idx=t-48; idx<512; idx+=208){
      int tk = idx>>3, q = idx&7;
      if (q<4) *(u16x4*)&Vh[tk][48+(q&3)*4] = z4;
      else     *(u16x4*)&Vl[tk][48+(q&3)*4] = z4;
    }
  }
  __syncthreads();

  // hoist P fragments (constant across all V chunks)
  bf16x8 pfh[3][2], pfl[3][2];
  #pragma unroll
  for (int it=0;it<3;it++)
    #pragma unroll
    for (int ks=0;ks<2;ks++){
      pfh[it][ks] = *(const bf16x8*)&Ph[it*16+lr][ks*32+g*8];
      pfl[it][ks] = *(const bf16x8*)&Pl[it*16+lr][ks*32+g*8];
    }

  for (int vc=0; vc<16; vc++){
    #pragma unroll
    for (int l=0;l<3;l++){
      const float xv[4] = {pv[l].x, pv[l].y, pv[l].z, pv[l].w};
      u16x4 hv, lv;
      #pragma unroll
      for (int c=0;c<4;c++){
        unsigned short hh = f2bf(xv[c]);
        hv[c] = hh; lv[c] = f2bf(xv[c] - bf2f(hh));
      }
      *(u16x4*)&Vh[vtk[l]][vgrp[l]*4] = hv;
      *(u16x4*)&Vl[vtk[l]][vgrp[l]*4] = lv;
    }
    __syncthreads();
    if (vc < 15){
      #pragma unroll
      for (int l=0;l<3;l++)
        pv[l] = *(const float4*)(qkv + base + (size_t)((vc+1)*64+vtk[l])*1152 + 768 + vgrp[l]*4);
    }
    bf16x8 vfh[2], vfl[2];
    #pragma unroll
    for (int ks=0;ks<2;ks++){
      vfh[ks] = *(const bf16x8*)&Vh[w*16+lr][ks*32+g*8];
      vfl[ks] = *(const bf16x8*)&Vl[w*16+lr][ks*32+g*8];
    }
    f32x4v o[3];
    #pragma unroll
    for (int it=0;it<3;it++) o[it] = (f32x4v){0.f,0.f,0.f,0.f};
    #pragma unroll
    for (int it=0;it<3;it++)
      #pragma unroll
      for (int ks=0;ks<2;ks++){
        o[it] = __builtin_amdgcn_mfma_f32_16x16x32_bf16(pfh[it][ks], vfh[ks], o[it], 0,0,0);
        o[it] = __builtin_amdgcn_mfma_f32_16x16x32_bf16(pfl[it][ks], vfh[ks], o[it], 0,0,0);
        o[it] = __builtin_amdgcn_mfma_f32_16x16x32_bf16(pfh[it][ks], vfl[ks], o[it], 0,0,0);
      }
    const int n = vc*64 + w*16 + lr;
    #pragma unroll
    for (int it=0;it<3;it++){
      float* dst = co + ((size_t)b*NN + n)*DD + h*48 + it*16 + g*4;
      *(float4*)dst = *(float4*)&o[it];
    }
    __syncthreads();
  }
}

// ---------------- tiled fp32 GEMM (kept for small batched GEMMs) ----------------
template<bool AT_, bool BT_, bool BIAS_, bool RES_>
__global__ __launch_bounds__(256) void gemm64_kernel(const float* __restrict__ A,
    const float* __restrict__ Bm, const float* __restrict__ bias,
    const float* __restrict__ res, float* __restrict__ Cc,
    int M, int Nd, int K, size_t sA, size_t sB, size_t sC)
{
  A  += (size_t)blockIdx.z*sA;
  Bm += (size_t)blockIdx.z*sB;
  Cc += (size_t)blockIdx.z*sC;
  const float* resp = RES_ ? res + (size_t)blockIdx.z*sC : nullptr;
  const int m0 = blockIdx.y*64, n0 = blockIdx.x*64;
  const int t = threadIdx.x, tx = t&15, ty = t>>4;
  __shared__ float As[16][68];
  __shared__ float Bs[16][68];
  float acc[4][4];
  #pragma unroll
  for (int i=0;i<4;i++)
    #pragma unroll
    for (int j=0;j<4;j++) acc[i][j]=0.f;

  for (int k0=0;k0<K;k0+=16){
    if (!AT_){
      const int r = t>>2, c4 = t&3;
      float4 av = *(const float4*)(A + (size_t)(m0+r)*K + k0 + c4*4);
      As[c4*4+0][r]=av.x; As[c4*4+1][r]=av.y; As[c4*4+2][r]=av.z; As[c4*4+3][r]=av.w;
    } else {
      const int r = t>>4, c4 = t&15;
      float4 av = *(const float4*)(A + (size_t)(k0+r)*M + m0 + c4*4);
      *(float4*)&As[r][c4*4] = av;
    }
    if (!BT_){
      const int r = t>>4, c4 = t&15;
      float4 bv = *(const float4*)(Bm + (size_t)(k0+r)*Nd + n0 + c4*4);
      *(float4*)&Bs[r][c4*4] = bv;
    } else {
      const int r = t>>2, c4 = t&3;
      float4 bv = *(const float4*)(Bm + (size_t)(n0+r)*K + k0 + c4*4);
      Bs[c4*4+0][r]=bv.x; Bs[c4*4+1][r]=bv.y; Bs[c4*4+2][r]=bv.z; Bs[c4*4+3][r]=bv.w;
    }
    __syncthreads();
    #pragma unroll
    for (int k=0;k<16;k++){
      const float4 a4 = *(const float4*)&As[k][ty*4];
      const float4 b4 = *(const float4*)&Bs[k][tx*4];
      float a_[4] = {a4.x,a4.y,a4.z,a4.w};
      float b_[4] = {b4.x,b4.y,b4.z,b4.w};
      #pragma unroll
      for (int i=0;i<4;i++)
        #pragma unroll
        for (int j=0;j<4;j++) acc[i][j] += a_[i]*b_[j];
    }
    __syncthreads();
  }
  float bv_[4];
  if (BIAS_){
    #pragma unroll
    for (int j=0;j<4;j++) bv_[j] = bias[n0 + tx*4 + j];
  }
  #pragma unroll
  for (int i=0;i<4;i++){
    const size_t row = (size_t)(m0 + ty*4 + i);
    float* Crow = Cc + row*Nd + n0 + tx*4;
    const float* Rrow = RES_ ? (resp + row*Nd + n0 + tx*4) : nullptr;
    #pragma unroll
    for (int j=0;j<4;j++){
      float v = acc[i][j];
      if (BIAS_) v += bv_[j];
      if (RES_)  v += Rrow[j];
      Crow[j] = v;
    }
  }
}

// ---------------- weight prep: transpose [K,N] -> bf16 hi/lo [N][K] ----------------
__global__ __launch_bounds__(256) void wconv_t_kernel(const float* __restrict__ in,
    unsigned short* __restrict__ oh, unsigned short* __restrict__ ol, int K, int N){
  __shared__ float tile[32][33];
  const int n0 = blockIdx.x*32, k0 = blockIdx.y*32;
  const int j = threadIdx.x & 31, i4 = threadIdx.x >> 5;
  #pragma unroll
  for (int s=0;s<4;s++){
    int i = i4*4+s;
    tile[i][j] = in[(size_t)(k0+i)*N + n0 + j];
  }
  __syncthreads();
  #pragma unroll
  for (int s=0;s<4;s++){
    int i = i4*4+s;
    float x = tile[j][i];                       // in[k0+j][n0+i]
    unsigned short h = f2bf(x);
    oh[(size_t)(n0+i)*K + k0 + j] = h;
    ol[(size_t)(n0+i)*K + k0 + j] = f2bf(x - bf2f(h));
  }
}

// ---------------- weight prep: convert-only (already [N,K]) ----------------
__global__ __launch_bounds__(256) void wconv_kernel(const float* __restrict__ in,
    unsigned short* __restrict__ oh, unsigned short* __restrict__ ol, int n){
  int i = blockIdx.x*256 + threadIdx.x;
  if (i < n){
    float x = in[i];
    unsigned short h = f2bf(x);
    oh[i] = h;
    ol[i] = f2bf(x - bf2f(h));
  }
}

// ---------------- bf16x3 split-precision MFMA GEMM ----------------
template<bool BIAS_, bool RES_>
__global__ __launch_bounds__(256) void gemm_bf16x3_kernel(const float* __restrict__ A,
    const unsigned short* __restrict__ Bh, const unsigned short* __restrict__ Bl,
    const float* __restrict__ bias, const float* __restrict__ res,
    float* __restrict__ C, int M, int N, int K)
{
  const int t = threadIdx.x;
  const int m0 = blockIdx.y*128, n0 = blockIdx.x*128;
  __shared__ unsigned short As_h[128][40];
  __shared__ unsigned short As_l[128][40];
  __shared__ unsigned short Bs_h[128][40];
  __shared__ unsigned short Bs_l[128][40];

  const float* Ab = A + (size_t)m0*K;
  const unsigned short* Bhb = Bh + (size_t)n0*K;
  const unsigned short* Blb = Bl + (size_t)n0*K;

  f32x4v acc[4][4];
  #pragma unroll
  for (int i=0;i<4;i++)
    #pragma unroll
    for (int j=0;j<4;j++) acc[i][j] = (f32x4v){0.f,0.f,0.f,0.f};

  const int w  = t >> 6;
  const int wm = w >> 1, wn = w & 1;
  const int lr = t & 15, g = (t & 63) >> 4;
  const int ac = t & 7,  ar0 = t >> 3;
  const int brow = t >> 1, bc0 = (t & 1)*2;

  for (int k0 = 0; k0 < K; k0 += 32){
    #pragma unroll
    for (int p=0;p<4;p++){
      const int row = ar0 + p*32;
      const float4 v = *(const float4*)(Ab + (size_t)row*K + k0 + ac*4);
      const float xs[4] = {v.x, v.y, v.z, v.w};
      u16x4 hv, lv;
      #pragma unroll
      for (int j2=0;j2<4;j2++){
        unsigned short hh = f2bf(xs[j2]);
        hv[j2] = hh;
        lv[j2] = f2bf(xs[j2] - bf2f(hh));
      }
      *(u16x4*)&As_h[row][ac*4] = hv;
      *(u16x4*)&As_l[row][ac*4] = lv;
    }
    #pragma unroll
    for (int c=0;c<2;c++){
      const int cc = bc0 + c;
      *(uint4*)&Bs_h[brow][cc*8] = *(const uint4*)(Bhb + (size_t)brow*K + k0 + cc*8);
      *(uint4*)&Bs_l[brow][cc*8] = *(const uint4*)(Blb + (size_t)brow*K + k0 + cc*8);
    }
    __syncthreads();

    bf16x8 ah[4], al[4], bhf[4], blf[4];
    #pragma unroll
    for (int i=0;i<4;i++){
      ah[i]  = *(const bf16x8*)&As_h[wm*64 + i*16 + lr][g*8];
      al[i]  = *(const bf16x8*)&As_l[wm*64 + i*16 + lr][g*8];
      bhf[i] = *(const bf16x8*)&Bs_h[wn*64 + i*16 + lr][g*8];
      blf[i] = *(const bf16x8*)&Bs_l[wn*64 + i*16 + lr][g*8];
    }
    #pragma unroll
    for (int mi=0;mi<4;mi++)
      #pragma unroll
      for (int ni=0;ni<4;ni++){
        f32x4v c_ = acc[mi][ni];
        c_ = __builtin_amdgcn_mfma_f32_16x16x32_bf16(ah[mi], bhf[ni], c_, 0,0,0);
        c_ = __builtin_amdgcn_mfma_f32_16x16x32_bf16(al[mi], bhf[ni], c_, 0,0,0);
        c_ = __builtin_amdgcn_mfma_f32_16x16x32_bf16(ah[mi], blf[ni], c_, 0,0,0);
        acc[mi][ni] = c_;
      }
    __syncthreads();
  }

  #pragma unroll
  for (int ni=0;ni<4;ni++){
    const int col = n0 + wn*64 + ni*16 + lr;
    const float bb = BIAS_ ? bias[col] : 0.f;
    #pragma unroll
    for (int mi=0;mi<4;mi++){
      const int r0 = m0 + wm*64 + mi*16 + g*4;
      #pragma unroll
      for (int r=0;r<4;r++){
        float v = acc[mi][ni][r] + bb;
        if (RES_) v += res[(size_t)(r0+r)*N + col];
        C[(size_t)(r0+r)*N + col] = v;
      }
    }
  }
}

// ---------------- LN(rep) + concat residual -> tx ----------------
__global__ __launch_bounds__(256) void ln_concat_kernel(const float* __restrict__ rep,
    const float* __restrict__ g, const float* __restrict__ b,
    const float* __restrict__ ch1, const float* __restrict__ ch2,
    float* __restrict__ tx){
  const int row = blockIdx.x;
  const float* x = rep + (size_t)row*D2;
  float s=0.f;
  for (int i=threadIdx.x;i<D2;i+=256) s += x[i];
  s = blockReduceSum256(s);
  const float mu = s / (float)D2;
  float v=0.f;
  for (int i=threadIdx.x;i<D2;i+=256){ float d = x[i]-mu; v += d*d; }
  v = blockReduceSum256(v);
  const float rs = rsqrtf(v/(float)D2 + 1e-5f);
  float* o = tx + (size_t)row*D2;
  for (int i=threadIdx.x;i<D2;i+=256){
    float val = (x[i]-mu)*rs*g[i] + b[i];
    float rv = (i<DD) ? ch1[(size_t)row*DD + i] : ch2[(size_t)row*DD + i - DD];
    o[i] = val + rv;
  }
}

// ---------------- depthwise 3x3 conv + bias + exact GELU ----------------
__global__ __launch_bounds__(256) void dwconv_gelu_kernel(const float* __restrict__ h1,
    const float* __restrict__ w, const float* __restrict__ bias, float* __restrict__ g){
  const int n = blockIdx.x & (NN-1);
  const int b = blockIdx.x >> 10;
  const int hh = n >> 5, ww = n & 31;
  const float* base = h1 + (size_t)b*NN*C2;
  for (int c = threadIdx.x; c < C2; c += 256){
    float acc = bias[c];
    const float* wc = w + (size_t)c*9;
    #pragma unroll
    for (int dh=-1;dh<=1;dh++){
      int h2 = hh+dh; if ((unsigned)h2 >= 32u) continue;
      #pragma unroll
      for (int dw=-1;dw<=1;dw++){
        int w2 = ww+dw; if ((unsigned)w2 >= 32u) continue;
        acc += base[(size_t)(h2*32+w2)*C2 + c] * wc[(dh+1)*3 + (dw+1)];
      }
    }
    float r = 0.5f*acc*(1.f + erff(acc*0.70710678118654752f));
    g[((size_t)b*NN + n)*C2 + c] = r;
  }
}

// ---------------- launch ----------------
extern "C" void kernel_launch(void* const* d_in, const int* in_sizes, int n_in,
                              void* d_out, int out_size, void* d_ws, size_t ws_size,
                              hipStream_t stream) {
  const float* x1     = (const float*)d_in[0];
  const float* x2     = (const float*)d_in[1];
  const float* ln1_g  = (const float*)d_in[2];
  const float* ln1_b  = (const float*)d_in[3];
  const float* qkv_w  = (const float*)d_in[4];
  const float* ca_temp= (const float*)d_in[5];
  const float* proj_w = (const float*)d_in[6];
  const float* proj_b = (const float*)d_in[7];
  const float* ln3_g  = (const float*)d_in[8];
  const float* ln3_b  = (const float*)d_in[9];
  const float* rp_w   = (const float*)d_in[10];
  const float* rp_b   = (const float*)d_in[11];
  const float* cn_g   = (const float*)d_in[12];
  const float* cn_b   = (const float*)d_in[13];
  const float* ln2_g  = (const float*)d_in[14];
  const float* ln2_b  = (const float*)d_in[15];
  const float* fc1_w  = (const float*)d_in[16];
  const float* fc1_b  = (const float*)d_in[17];
  const float* dw_w   = (const float*)d_in[18];
  const float* dw_b   = (const float*)d_in[19];
  const float* fc2_w  = (const float*)d_in[20];
  const float* fc2_b  = (const float*)d_in[21];
  float* out = (float*)d_out;
  float* W   = (float*)d_ws;

  // ---- workspace layout (peak 50,331,648 floats = 192 MiB) ----
  float* yco  = W;
  float* qkvb = W + (size_t)SZ_ND;
  float* ch1  = W + 25165824ull;
  float* ch2  = W + 31457280ull;
  unsigned short* qkvwT_h  = (unsigned short*)(W + 37748736ull);
  unsigned short* qkvwT_l  = qkvwT_h + 442368u;
  unsigned short* projwT_h = qkvwT_l + 442368u;
  unsigned short* projwT_l = projwT_h + 147456u;
  float* n1  = W;
  float* n2  = W + (size_t)SZ_ND;
  float* KS  = W + 2ull*SZ_ND;
  float* QS  = W + 3ull*SZ_ND;
  float* ctx = W + (size_t)SZ_ND;
  float* ATb = W;
  float* rep = W + (size_t)SZ_ND;
  unsigned short* rpw_h = (unsigned short*)(W + 37748736ull);
  unsigned short* rpw_l = rpw_h + 294912u;
  float* txp  = out;
  float* h1   = W;
  float* y2   = W + (size_t)SZ_NC2;
  float* gbuf = W + (size_t)SZ_NC2;
  unsigned short* fc1wT_h = (unsigned short*)(W + 37748736ull);
  unsigned short* fc1wT_l = fc1wT_h + 1179648u;
  unsigned short* fc2wT_h = (unsigned short*)W;
  unsigned short* fc2wT_l = fc2wT_h + 1179648u;

  const int M = BN*NN;

  // ---- phase-A weight prep ----
  wconv_t_kernel<<<dim3(1152/32, DD/32), dim3(256), 0, stream>>>(qkv_w, qkvwT_h, qkvwT_l, DD, 1152);
  wconv_t_kernel<<<dim3(DD/32, DD/32), dim3(256), 0, stream>>>(proj_w, projwT_h, projwT_l, DD, DD);

  // ---- channel attention, stream 1 ----
  ln_kernel<<<dim3(M), dim3(256), 0, stream>>>(x1, ln1_g, ln1_b, yco, DD);
  gemm_bf16x3_kernel<false,false><<<dim3(1152/128, M/128), dim3(256), 0, stream>>>(
      yco, qkvwT_h, qkvwT_l, nullptr, nullptr, qkvb, M, 1152, DD);
  chattn_mfma_kernel<<<dim3(BN*NHEAD), dim3(256), 0, stream>>>(qkvb, ca_temp, yco);
  gemm_bf16x3_kernel<true,true><<<dim3(DD/128, M/128), dim3(256), 0, stream>>>(
      yco, projwT_h, projwT_l, proj_b, x1, ch1, M, DD, DD);

  // ---- channel attention, stream 2 ----
  ln_kernel<<<dim3(M), dim3(256), 0, stream>>>(x2, ln1_g, ln1_b, yco, DD);
  gemm_bf16x3_kernel<false,false><<<dim3(1152/128, M/128), dim3(256), 0, stream>>>(
      yco, qkvwT_h, qkvwT_l, nullptr, nullptr, qkvb, M, 1152, DD);
  chattn_mfma_kernel<<<dim3(BN*NHEAD), dim3(256), 0, stream>>>(qkvb, ca_temp, yco);
  gemm_bf16x3_kernel<true,true><<<dim3(DD/128, M/128), dim3(256), 0, stream>>>(
      yco, projwT_h, projwT_l, proj_b, x2, ch2, M, DD, DD);

  // ---- cross attention ----
  wconv_kernel<<<dim3(294912/256), dim3(256), 0, stream>>>(rp_w, rpw_h, rpw_l, 294912);
  ln_kernel<<<dim3(M), dim3(256), 0, stream>>>(ch1, ln3_g, ln3_b, n1, DD);
  ln_kernel<<<dim3(M), dim3(256), 0, stream>>>(ch2, ln3_g, ln3_b, n2, DD);
  rowsoftmax_kernel<<<dim3(M), dim3(256), 0, stream>>>(n2, QS, DD);
  colsoftmax_kernel<<<dim3(DD/64, BN), dim3(256), 0, stream>>>(n2, KS);
  gemm64_kernel<true,false,false,false><<<dim3(DD/64, DD/64, BN), dim3(256), 0, stream>>>(
      KS, n1, nullptr, nullptr, ctx, DD, DD, NN,
      (size_t)NN*DD, (size_t)NN*DD, (size_t)DD*DD);
  gemm64_kernel<false,false,false,false><<<dim3(DD/64, NN/64, BN), dim3(256), 0, stream>>>(
      QS, ctx, nullptr, nullptr, ATb, NN, DD, DD,
      (size_t)NN*DD, (size_t)DD*DD, (size_t)NN*DD);
  gemm_bf16x3_kernel<true,false><<<dim3(D2/128, M/128), dim3(256), 0, stream>>>(
      ATb, rpw_h, rpw_l, rp_b, nullptr, rep, M, D2, DD);
  ln_concat_kernel<<<dim3(M), dim3(256), 0, stream>>>(rep, cn_g, cn_b, ch1, ch2, txp);

  // ---- mix FFN ----
  wconv_t_kernel<<<dim3(C2/32, D2/32), dim3(256), 0, stream>>>(fc1_w, fc1wT_h, fc1wT_l, D2, C2);
  ln_kernel<<<dim3(M), dim3(256), 0, stream>>>(txp, ln2_g, ln2_b, y2, D2);
  gemm_bf16x3_kernel<true,false><<<dim3(C2/128, M/128), dim3(256), 0, stream>>>(
      y2, fc1wT_h, fc1wT_l, fc1_b, nullptr, h1, M, C2, D2);
  dwconv_gelu_kernel<<<dim3(M), dim3(256), 0, stream>>>(h1, dw_w, dw_b, gbuf);
  wconv_t_kernel<<<dim3(D2/32, C2/32), dim3(256), 0, stream>>>(fc2_w, fc2wT_h, fc2wT_l, C2, D2);
  gemm_bf16x3_kernel<true,true><<<dim3(D2/128, M/128), dim3(256), 0, stream>>>(
      gbuf, fc2wT_h, fc2wT_l, fc2_b, txp, out, M, D2, C2);
}

// Round 3
// 1189.243 us; speedup vs baseline: 2.4438x; 1.1674x over previous
//
#include <hip/hip_runtime.h>
#include <math.h>

#define BN 16
#define NN 1024
#define DD 384
#define D2 768
#define C2 1536
#define NHEAD 8
#define DH 48

#define SZ_ND   (BN*NN*DD)      /* 6291456  */
#define SZ_N2D  (BN*NN*D2)      /* 12582912 */
#define SZ_NC2  (BN*NN*C2)      /* 25165824 */
#define SZ_QKV  (BN*NN*3*DD)    /* 18874368 */

typedef __bf16 bf16x8 __attribute__((ext_vector_type(8)));
typedef float f32x4v __attribute__((ext_vector_type(4)));
typedef unsigned short u16x4 __attribute__((ext_vector_type(4)));

__device__ __forceinline__ unsigned short f2bf(float x){
  unsigned int u = __float_as_uint(x);
  u += 0x7FFFu + ((u >> 16) & 1u);          // round-nearest-even to bf16
  return (unsigned short)(u >> 16);
}
__device__ __forceinline__ float bf2f(unsigned short h){
  return __uint_as_float(((unsigned int)h) << 16);
}

// ---------------- block reductions (256 threads = 4 waves) ----------------
__device__ __forceinline__ float blockReduceSum256(float v){
  __shared__ float red[4];
  #pragma unroll
  for (int o=32;o;o>>=1) v += __shfl_down(v,o,64);
  if ((threadIdx.x&63)==0) red[threadIdx.x>>6]=v;
  __syncthreads();
  float r = red[0]+red[1]+red[2]+red[3];
  __syncthreads();
  return r;
}
__device__ __forceinline__ float blockReduceMax256(float v){
  __shared__ float red[4];
  #pragma unroll
  for (int o=32;o;o>>=1) v = fmaxf(v, __shfl_down(v,o,64));
  if ((threadIdx.x&63)==0) red[threadIdx.x>>6]=v;
  __syncthreads();
  float r = fmaxf(fmaxf(red[0],red[1]),fmaxf(red[2],red[3]));
  __syncthreads();
  return r;
}

// ---------------- LayerNorm: one block per row ----------------
__global__ __launch_bounds__(256) void ln_kernel(const float* __restrict__ in,
    const float* __restrict__ g, const float* __restrict__ b,
    float* __restrict__ out, int C){
  const int row = blockIdx.x;
  const float* x = in + (size_t)row*C;
  float s=0.f;
  for (int i=threadIdx.x;i<C;i+=256) s += x[i];
  s = blockReduceSum256(s);
  const float mu = s / (float)C;
  float v=0.f;
  for (int i=threadIdx.x;i<C;i+=256){ float d = x[i]-mu; v += d*d; }
  v = blockReduceSum256(v);
  const float rs = rsqrtf(v/(float)C + 1e-5f);
  float* o = out + (size_t)row*C;
  for (int i=threadIdx.x;i<C;i+=256) o[i] = (x[i]-mu)*rs*g[i] + b[i];
}

// ---------------- row softmax (QS: softmax over channels d) ----------------
__global__ __launch_bounds__(256) void rowsoftmax_kernel(const float* __restrict__ in,
    float* __restrict__ out, int C){
  const int row = blockIdx.x;
  const float* x = in + (size_t)row*C;
  float m = -3.0e38f;
  for (int i=threadIdx.x;i<C;i+=256) m = fmaxf(m, x[i]);
  m = blockReduceMax256(m);
  float s = 0.f;
  for (int i=threadIdx.x;i<C;i+=256) s += expf(x[i]-m);
  s = blockReduceSum256(s);
  const float inv = 1.f/s;
  float* o = out + (size_t)row*C;
  for (int i=threadIdx.x;i<C;i+=256) o[i] = expf(x[i]-m)*inv;
}

// ---------------- column softmax over tokens n (KS) ----------------
__global__ __launch_bounds__(256) void colsoftmax_kernel(const float* __restrict__ in,
    float* __restrict__ out){
  const int dl = threadIdx.x & 63;
  const int nc = threadIdx.x >> 6;
  const int d  = blockIdx.x*64 + dl;
  const int b  = blockIdx.y;
  const float* p = in + (size_t)b*NN*DD + d;
  __shared__ float redm[4][64];
  __shared__ float reds[4][64];
  float m = -3.0e38f;
  for (int n=nc*256; n<nc*256+256; n++) m = fmaxf(m, p[(size_t)n*DD]);
  redm[nc][dl] = m; __syncthreads();
  m = fmaxf(fmaxf(redm[0][dl],redm[1][dl]),fmaxf(redm[2][dl],redm[3][dl]));
  float s=0.f;
  for (int n=nc*256;n<nc*256+256;n++) s += expf(p[(size_t)n*DD]-m);
  reds[nc][dl]=s; __syncthreads();
  s = reds[0][dl]+reds[1][dl]+reds[2][dl]+reds[3][dl];
  const float inv = 1.f/s;
  float* q = out + (size_t)b*NN*DD + d;
  for (int n=nc*256;n<nc*256+256;n++) q[(size_t)n*DD] = expf(p[(size_t)n*DD]-m)*inv;
}

// ---------------- channel attention, MFMA version: one block per (b,h) ----------------
__global__ __launch_bounds__(256) void chattn_mfma_kernel(
    const float* __restrict__ qkv, const float* __restrict__ temp,
    float* __restrict__ co)
{
  const int bh = blockIdx.x, b = bh >> 3, h = bh & 7;
  const int t = threadIdx.x, w = t >> 6, lane = t & 63;
  const int lr = lane & 15, g = lane >> 4;

  __shared__ __align__(16) unsigned char ldsA[27648];
  unsigned short (*Qh)[72] = (unsigned short(*)[72])(ldsA);
  unsigned short (*Ql)[72] = (unsigned short(*)[72])(ldsA + 6912);
  unsigned short (*Kh)[72] = (unsigned short(*)[72])(ldsA + 13824);
  unsigned short (*Kl)[72] = (unsigned short(*)[72])(ldsA + 20736);
  unsigned short (*Vh)[72] = (unsigned short(*)[72])(ldsA);
  unsigned short (*Vl)[72] = (unsigned short(*)[72])(ldsA + 9216);
  __shared__ unsigned short Ph[48][72], Pl[48][72];
  __shared__ float S[48][49];
  __shared__ float qn[48], kn[48];

  const size_t base = (size_t)b*NN*1152 + (size_t)h*48;

  int agrp[3], apr[3], aoff[3];
  #pragma unroll
  for (int l=0;l<3;l++){
    int idx = l*256+t;
    int mo = (idx>=384) ? 1 : 0;
    int a = idx - mo*384;
    agrp[l] = a%12; apr[l] = a/12; aoff[l] = mo*384;
  }

  f32x4v acc[12];
  #pragma unroll
  for (int i=0;i<12;i++) acc[i] = (f32x4v){0.f,0.f,0.f,0.f};

  float4 cur[3][2];
  #pragma unroll
  for (int l=0;l<3;l++){
    const float* p = qkv + base + (size_t)(apr[l]*2)*1152 + aoff[l] + agrp[l]*4;
    cur[l][0] = *(const float4*)p;
    cur[l][1] = *(const float4*)(p+1152);
  }

  for (int nc=0; nc<16; nc++){
    #pragma unroll
    for (int l=0;l<3;l++){
      unsigned short (*Dh)[72] = aoff[l] ? Kh : Qh;
      unsigned short (*Dl)[72] = aoff[l] ? Kl : Ql;
      const float x0[4] = {cur[l][0].x, cur[l][0].y, cur[l][0].z, cur[l][0].w};
      const float x1[4] = {cur[l][1].x, cur[l][1].y, cur[l][1].z, cur[l][1].w};
      #pragma unroll
      for (int c=0;c<4;c++){
        int d = agrp[l]*4+c;
        unsigned short h0 = f2bf(x0[c]), h1 = f2bf(x1[c]);
        unsigned short l0 = f2bf(x0[c]-bf2f(h0)), l1 = f2bf(x1[c]-bf2f(h1));
        *(unsigned int*)&Dh[d][apr[l]*2] = (unsigned)h0 | ((unsigned)h1<<16);
        *(unsigned int*)&Dl[d][apr[l]*2] = (unsigned)l0 | ((unsigned)l1<<16);
      }
    }
    __syncthreads();
    if (nc < 15){
      #pragma unroll
      for (int l=0;l<3;l++){
        const float* p = qkv + base + (size_t)((nc+1)*64 + apr[l]*2)*1152 + aoff[l] + agrp[l]*4;
        cur[l][0] = *(const float4*)p;
        cur[l][1] = *(const float4*)(p+1152);
      }
    }
    if (w < 3){
      #pragma unroll
      for (int ks=0;ks<2;ks++){
        bf16x8 a_h = *(const bf16x8*)&Qh[w*16+lr][ks*32+g*8];
        bf16x8 a_l = *(const bf16x8*)&Ql[w*16+lr][ks*32+g*8];
        #pragma unroll
        for (int c=0;c<3;c++){
          bf16x8 b_h = *(const bf16x8*)&Kh[c*16+lr][ks*32+g*8];
          bf16x8 b_l = *(const bf16x8*)&Kl[c*16+lr][ks*32+g*8];
          acc[c] = __builtin_amdgcn_mfma_f32_16x16x32_bf16(a_h, b_h, acc[c], 0,0,0);
          acc[c] = __builtin_amdgcn_mfma_f32_16x16x32_bf16(a_l, b_h, acc[c], 0,0,0);
          acc[c] = __builtin_amdgcn_mfma_f32_16x16x32_bf16(a_h, b_l, acc[c], 0,0,0);
        }
      }
    } else {
      #pragma unroll
      for (int ks=0;ks<2;ks++){
        #pragma unroll
        for (int c=0;c<3;c++){
          bf16x8 qh_ = *(const bf16x8*)&Qh[c*16+lr][ks*32+g*8];
          bf16x8 ql_ = *(const bf16x8*)&Ql[c*16+lr][ks*32+g*8];
          bf16x8 kh_ = *(const bf16x8*)&Kh[c*16+lr][ks*32+g*8];
          bf16x8 kl_ = *(const bf16x8*)&Kl[c*16+lr][ks*32+g*8];
          acc[c]   = __builtin_amdgcn_mfma_f32_16x16x32_bf16(qh_, qh_, acc[c],   0,0,0);
          acc[3+c] = __builtin_amdgcn_mfma_f32_16x16x32_bf16(qh_, ql_, acc[3+c], 0,0,0);
          acc[6+c] = __builtin_amdgcn_mfma_f32_16x16x32_bf16(kh_, kh_, acc[6+c], 0,0,0);
          acc[9+c] = __builtin_amdgcn_mfma_f32_16x16x32_bf16(kh_, kl_, acc[9+c], 0,0,0);
        }
      }
    }
    __syncthreads();
  }

  const float tp = temp[h];
  if (w == 3){
    if ((lane>>4) == ((lane&15)>>2)){
      int p = lane & 15, r = p & 3;
      #pragma unroll
      for (int c=0;c<3;c++){
        float q2 = fmaxf(acc[c][r]   + 2.f*acc[3+c][r], 0.f);
        float k2 = fmaxf(acc[6+c][r] + 2.f*acc[9+c][r], 0.f);
        qn[c*16+p] = fmaxf(sqrtf(q2), 1e-12f);
        kn[c*16+p] = fmaxf(sqrtf(k2), 1e-12f);
      }
    }
  }
  __syncthreads();
  if (w < 3){
    #pragma unroll
    for (int c=0;c<3;c++){
      #pragma unroll
      for (int r=0;r<4;r++){
        int i = w*16 + g*4 + r, j = c*16 + lr;
        S[i][j] = acc[c][r]*tp/(qn[i]*kn[j]);
      }
    }
  }
  __syncthreads();

  int vgrp[3], vtk[3];
  #pragma unroll
  for (int l=0;l<3;l++){ int idx=l*256+t; vtk[l]=idx/12; vgrp[l]=idx%12; }
  float4 pv[3];
  #pragma unroll
  for (int l=0;l<3;l++)
    pv[l] = *(const float4*)(qkv + base + (size_t)vtk[l]*1152 + 768 + vgrp[l]*4);

  if (t < 48){
    float m = -3.0e38f;
    for (int j=0;j<48;j++) m = fmaxf(m, S[t][j]);
    float s = 0.f;
    for (int j=0;j<48;j++){ float e_ = expf(S[t][j]-m); S[t][j] = e_; s += e_; }
    float inv = 1.f/s;
    for (int j=0;j<48;j++){
      float p = S[t][j]*inv;
      unsigned short hp = f2bf(p);
      Ph[t][j] = hp; Pl[t][j] = f2bf(p - bf2f(hp));
    }
    #pragma unroll
    for (int j=48;j<64;j++){ Ph[t][j]=0; Pl[t][j]=0; }
  } else {
    const u16x4 z4 = (u16x4){0,0,0,0};
    for (int idx=t-48; idx<512; idx+=208){
      int tk = idx>>3, q = idx&7;
      if (q<4) *(u16x4*)&Vh[tk][48+(q&3)*4] = z4;
      else     *(u16x4*)&Vl[tk][48+(q&3)*4] = z4;
    }
  }
  __syncthreads();

  bf16x8 pfh[3][2], pfl[3][2];
  #pragma unroll
  for (int it=0;it<3;it++)
    #pragma unroll
    for (int ks=0;ks<2;ks++){
      pfh[it][ks] = *(const bf16x8*)&Ph[it*16+lr][ks*32+g*8];
      pfl[it][ks] = *(const bf16x8*)&Pl[it*16+lr][ks*32+g*8];
    }

  for (int vc=0; vc<16; vc++){
    #pragma unroll
    for (int l=0;l<3;l++){
      const float xv[4] = {pv[l].x, pv[l].y, pv[l].z, pv[l].w};
      u16x4 hv, lv;
      #pragma unroll
      for (int c=0;c<4;c++){
        unsigned short hh = f2bf(xv[c]);
        hv[c] = hh; lv[c] = f2bf(xv[c] - bf2f(hh));
      }
      *(u16x4*)&Vh[vtk[l]][vgrp[l]*4] = hv;
      *(u16x4*)&Vl[vtk[l]][vgrp[l]*4] = lv;
    }
    __syncthreads();
    if (vc < 15){
      #pragma unroll
      for (int l=0;l<3;l++)
        pv[l] = *(const float4*)(qkv + base + (size_t)((vc+1)*64+vtk[l])*1152 + 768 + vgrp[l]*4);
    }
    bf16x8 vfh[2], vfl[2];
    #pragma unroll
    for (int ks=0;ks<2;ks++){
      vfh[ks] = *(const bf16x8*)&Vh[w*16+lr][ks*32+g*8];
      vfl[ks] = *(const bf16x8*)&Vl[w*16+lr][ks*32+g*8];
    }
    f32x4v o[3];
    #pragma unroll
    for (int it=0;it<3;it++) o[it] = (f32x4v){0.f,0.f,0.f,0.f};
    #pragma unroll
    for (int it=0;it<3;it++)
      #pragma unroll
      for (int ks=0;ks<2;ks++){
        o[it] = __builtin_amdgcn_mfma_f32_16x16x32_bf16(pfh[it][ks], vfh[ks], o[it], 0,0,0);
        o[it] = __builtin_amdgcn_mfma_f32_16x16x32_bf16(pfl[it][ks], vfh[ks], o[it], 0,0,0);
        o[it] = __builtin_amdgcn_mfma_f32_16x16x32_bf16(pfh[it][ks], vfl[ks], o[it], 0,0,0);
      }
    const int n = vc*64 + w*16 + lr;
    #pragma unroll
    for (int it=0;it<3;it++){
      float* dst = co + ((size_t)b*NN + n)*DD + h*48 + it*16 + g*4;
      *(float4*)dst = *(float4*)&o[it];
    }
    __syncthreads();
  }
}

// ---------------- tiled fp32 GEMM (kept for small batched GEMMs) ----------------
template<bool AT_, bool BT_, bool BIAS_, bool RES_>
__global__ __launch_bounds__(256) void gemm64_kernel(const float* __restrict__ A,
    const float* __restrict__ Bm, const float* __restrict__ bias,
    const float* __restrict__ res, float* __restrict__ Cc,
    int M, int Nd, int K, size_t sA, size_t sB, size_t sC)
{
  A  += (size_t)blockIdx.z*sA;
  Bm += (size_t)blockIdx.z*sB;
  Cc += (size_t)blockIdx.z*sC;
  const float* resp = RES_ ? res + (size_t)blockIdx.z*sC : nullptr;
  const int m0 = blockIdx.y*64, n0 = blockIdx.x*64;
  const int t = threadIdx.x, tx = t&15, ty = t>>4;
  __shared__ float As[16][68];
  __shared__ float Bs[16][68];
  float acc[4][4];
  #pragma unroll
  for (int i=0;i<4;i++)
    #pragma unroll
    for (int j=0;j<4;j++) acc[i][j]=0.f;

  for (int k0=0;k0<K;k0+=16){
    if (!AT_){
      const int r = t>>2, c4 = t&3;
      float4 av = *(const float4*)(A + (size_t)(m0+r)*K + k0 + c4*4);
      As[c4*4+0][r]=av.x; As[c4*4+1][r]=av.y; As[c4*4+2][r]=av.z; As[c4*4+3][r]=av.w;
    } else {
      const int r = t>>4, c4 = t&15;
      float4 av = *(const float4*)(A + (size_t)(k0+r)*M + m0 + c4*4);
      *(float4*)&As[r][c4*4] = av;
    }
    if (!BT_){
      const int r = t>>4, c4 = t&15;
      float4 bv = *(const float4*)(Bm + (size_t)(k0+r)*Nd + n0 + c4*4);
      *(float4*)&Bs[r][c4*4] = bv;
    } else {
      const int r = t>>2, c4 = t&3;
      float4 bv = *(const float4*)(Bm + (size_t)(n0+r)*K + k0 + c4*4);
      Bs[c4*4+0][r]=bv.x; Bs[c4*4+1][r]=bv.y; Bs[c4*4+2][r]=bv.z; Bs[c4*4+3][r]=bv.w;
    }
    __syncthreads();
    #pragma unroll
    for (int k=0;k<16;k++){
      const float4 a4 = *(const float4*)&As[k][ty*4];
      const float4 b4 = *(const float4*)&Bs[k][tx*4];
      float a_[4] = {a4.x,a4.y,a4.z,a4.w};
      float b_[4] = {b4.x,b4.y,b4.z,b4.w};
      #pragma unroll
      for (int i=0;i<4;i++)
        #pragma unroll
        for (int j=0;j<4;j++) acc[i][j] += a_[i]*b_[j];
    }
    __syncthreads();
  }
  float bv_[4];
  if (BIAS_){
    #pragma unroll
    for (int j=0;j<4;j++) bv_[j] = bias[n0 + tx*4 + j];
  }
  #pragma unroll
  for (int i=0;i<4;i++){
    const size_t row = (size_t)(m0 + ty*4 + i);
    float* Crow = Cc + row*Nd + n0 + tx*4;
    const float* Rrow = RES_ ? (resp + row*Nd + n0 + tx*4) : nullptr;
    #pragma unroll
    for (int j=0;j<4;j++){
      float v = acc[i][j];
      if (BIAS_) v += bv_[j];
      if (RES_)  v += Rrow[j];
      Crow[j] = v;
    }
  }
}

// ---------------- weight prep: transpose [K,N] -> bf16 hi/lo [N][K] ----------------
__global__ __launch_bounds__(256) void wconv_t_kernel(const float* __restrict__ in,
    unsigned short* __restrict__ oh, unsigned short* __restrict__ ol, int K, int N){
  __shared__ float tile[32][33];
  const int n0 = blockIdx.x*32, k0 = blockIdx.y*32;
  const int j = threadIdx.x & 31, i4 = threadIdx.x >> 5;
  #pragma unroll
  for (int s=0;s<4;s++){
    int i = i4*4+s;
    tile[i][j] = in[(size_t)(k0+i)*N + n0 + j];
  }
  __syncthreads();
  #pragma unroll
  for (int s=0;s<4;s++){
    int i = i4*4+s;
    float x = tile[j][i];                       // in[k0+j][n0+i]
    unsigned short h = f2bf(x);
    oh[(size_t)(n0+i)*K + k0 + j] = h;
    ol[(size_t)(n0+i)*K + k0 + j] = f2bf(x - bf2f(h));
  }
}

// ---------------- weight prep: convert-only (already [N,K]) ----------------
__global__ __launch_bounds__(256) void wconv_kernel(const float* __restrict__ in,
    unsigned short* __restrict__ oh, unsigned short* __restrict__ ol, int n){
  int i = blockIdx.x*256 + threadIdx.x;
  if (i < n){
    float x = in[i];
    unsigned short h = f2bf(x);
    oh[i] = h;
    ol[i] = f2bf(x - bf2f(h));
  }
}

// ---------------- bf16x3 split-precision MFMA GEMM ----------------
template<bool BIAS_, bool RES_>
__global__ __launch_bounds__(256) void gemm_bf16x3_kernel(const float* __restrict__ A,
    const unsigned short* __restrict__ Bh, const unsigned short* __restrict__ Bl,
    const float* __restrict__ bias, const float* __restrict__ res,
    float* __restrict__ C, int M, int N, int K)
{
  const int t = threadIdx.x;
  const int m0 = blockIdx.y*128, n0 = blockIdx.x*128;
  __shared__ unsigned short As_h[128][40];
  __shared__ unsigned short As_l[128][40];
  __shared__ unsigned short Bs_h[128][40];
  __shared__ unsigned short Bs_l[128][40];

  const float* Ab = A + (size_t)m0*K;
  const unsigned short* Bhb = Bh + (size_t)n0*K;
  const unsigned short* Blb = Bl + (size_t)n0*K;

  f32x4v acc[4][4];
  #pragma unroll
  for (int i=0;i<4;i++)
    #pragma unroll
    for (int j=0;j<4;j++) acc[i][j] = (f32x4v){0.f,0.f,0.f,0.f};

  const int w  = t >> 6;
  const int wm = w >> 1, wn = w & 1;
  const int lr = t & 15, g = (t & 63) >> 4;
  const int ac = t & 7,  ar0 = t >> 3;
  const int brow = t >> 1, bc0 = (t & 1)*2;

  for (int k0 = 0; k0 < K; k0 += 32){
    #pragma unroll
    for (int p=0;p<4;p++){
      const int row = ar0 + p*32;
      const float4 v = *(const float4*)(Ab + (size_t)row*K + k0 + ac*4);
      const float xs[4] = {v.x, v.y, v.z, v.w};
      u16x4 hv, lv;
      #pragma unroll
      for (int j2=0;j2<4;j2++){
        unsigned short hh = f2bf(xs[j2]);
        hv[j2] = hh;
        lv[j2] = f2bf(xs[j2] - bf2f(hh));
      }
      *(u16x4*)&As_h[row][ac*4] = hv;
      *(u16x4*)&As_l[row][ac*4] = lv;
    }
    #pragma unroll
    for (int c=0;c<2;c++){
      const int cc = bc0 + c;
      *(uint4*)&Bs_h[brow][cc*8] = *(const uint4*)(Bhb + (size_t)brow*K + k0 + cc*8);
      *(uint4*)&Bs_l[brow][cc*8] = *(const uint4*)(Blb + (size_t)brow*K + k0 + cc*8);
    }
    __syncthreads();

    bf16x8 ah[4], al[4], bhf[4], blf[4];
    #pragma unroll
    for (int i=0;i<4;i++){
      ah[i]  = *(const bf16x8*)&As_h[wm*64 + i*16 + lr][g*8];
      al[i]  = *(const bf16x8*)&As_l[wm*64 + i*16 + lr][g*8];
      bhf[i] = *(const bf16x8*)&Bs_h[wn*64 + i*16 + lr][g*8];
      blf[i] = *(const bf16x8*)&Bs_l[wn*64 + i*16 + lr][g*8];
    }
    #pragma unroll
    for (int mi=0;mi<4;mi++)
      #pragma unroll
      for (int ni=0;ni<4;ni++){
        f32x4v c_ = acc[mi][ni];
        c_ = __builtin_amdgcn_mfma_f32_16x16x32_bf16(ah[mi], bhf[ni], c_, 0,0,0);
        c_ = __builtin_amdgcn_mfma_f32_16x16x32_bf16(al[mi], bhf[ni], c_, 0,0,0);
        c_ = __builtin_amdgcn_mfma_f32_16x16x32_bf16(ah[mi], blf[ni], c_, 0,0,0);
        acc[mi][ni] = c_;
      }
    __syncthreads();
  }

  #pragma unroll
  for (int ni=0;ni<4;ni++){
    const int col = n0 + wn*64 + ni*16 + lr;
    const float bb = BIAS_ ? bias[col] : 0.f;
    #pragma unroll
    for (int mi=0;mi<4;mi++){
      const int r0 = m0 + wm*64 + mi*16 + g*4;
      #pragma unroll
      for (int r=0;r<4;r++){
        float v = acc[mi][ni][r] + bb;
        if (RES_) v += res[(size_t)(r0+r)*N + col];
        C[(size_t)(r0+r)*N + col] = v;
      }
    }
  }
}

// ---------------- LN(rep) + concat residual -> tx ----------------
__global__ __launch_bounds__(256) void ln_concat_kernel(const float* __restrict__ rep,
    const float* __restrict__ g, const float* __restrict__ b,
    const float* __restrict__ ch1, const float* __restrict__ ch2,
    float* __restrict__ tx){
  const int row = blockIdx.x;
  const float* x = rep + (size_t)row*D2;
  float s=0.f;
  for (int i=threadIdx.x;i<D2;i+=256) s += x[i];
  s = blockReduceSum256(s);
  const float mu = s / (float)D2;
  float v=0.f;
  for (int i=threadIdx.x;i<D2;i+=256){ float d = x[i]-mu; v += d*d; }
  v = blockReduceSum256(v);
  const float rs = rsqrtf(v/(float)D2 + 1e-5f);
  float* o = tx + (size_t)row*D2;
  for (int i=threadIdx.x;i<D2;i+=256){
    float val = (x[i]-mu)*rs*g[i] + b[i];
    float rv = (i<DD) ? ch1[(size_t)row*DD + i] : ch2[(size_t)row*DD + i - DD];
    o[i] = val + rv;
  }
}

// ---------------- depthwise 3x3 conv + bias + exact GELU (float4, sliding window) ----
// one thread per (b, h-row, 4-channel group); slides over w with 3x3 float4
// register window -> 3 loads/output instead of 9, all 16B coalesced.
__global__ __launch_bounds__(256) void dwconv_gelu_kernel(const float* __restrict__ h1,
    const float* __restrict__ w, const float* __restrict__ bias, float* __restrict__ g){
  const int idx = blockIdx.x*256 + threadIdx.x;   // 16*32*384 = 196608 total
  const int b   = idx / 12288;                    // 12288 = 32*384 (uniform per block)
  const int r   = idx - b*12288;
  const int hh  = r / 384;
  const int c4  = r - hh*384;
  const int c   = c4*4;
  const float* base = h1 + (size_t)b*NN*C2 + c;
  float* gout = g + ((size_t)b*NN + hh*32)*C2 + c;

  // per-channel 3x3 weights, vectorized over the 4 channels: wk[k][q] = w[(c+q)*9+k]
  f32x4v wk[9];
  #pragma unroll
  for (int k=0;k<9;k++){
    f32x4v t_;
    #pragma unroll
    for (int q=0;q<4;q++) t_[q] = w[(size_t)(c+q)*9 + k];
    wk[k] = t_;
  }
  f32x4v bvv;
  {
    const float4 bb = *(const float4*)(bias + c);
    bvv = (f32x4v){bb.x, bb.y, bb.z, bb.w};
  }

  const bool hm = (hh > 0), hp = (hh < 31);
  const f32x4v z4 = (f32x4v){0.f,0.f,0.f,0.f};
  const size_t rm = (size_t)((hh-1)*32)*C2;   // row offsets (only used if valid)
  const size_t r0 = (size_t)( hh   *32)*C2;
  const size_t rp = (size_t)((hh+1)*32)*C2;

  // window: rows 0..2 = (hh-1,hh,hh+1); cols A(w-1), B(w), C(w+1)
  f32x4v A0,A1,A2, B0,B1,B2, C0,C1,C2c;
  A0=z4; A1=z4; A2=z4;
  B0 = hm ? *(const f32x4v*)(base + rm) : z4;
  B1 =      *(const f32x4v*)(base + r0);
  B2 = hp ? *(const f32x4v*)(base + rp) : z4;
  C0 = hm ? *(const f32x4v*)(base + rm + C2) : z4;
  C1 =      *(const f32x4v*)(base + r0 + C2);
  C2c= hp ? *(const f32x4v*)(base + rp + C2) : z4;

  for (int ww=0; ww<32; ww++){
    // prefetch col ww+2 (overlaps compute)
    f32x4v N0,N1,N2;
    if (ww < 30){
      const size_t co_ = (size_t)(ww+2)*C2;
      N0 = hm ? *(const f32x4v*)(base + rm + co_) : z4;
      N1 =      *(const f32x4v*)(base + r0 + co_) ;
      N2 = hp ? *(const f32x4v*)(base + rp + co_) : z4;
    } else { N0=z4; N1=z4; N2=z4; }

    f32x4v s = bvv;
    s += wk[0]*A0 + wk[1]*B0 + wk[2]*C0;
    s += wk[3]*A1 + wk[4]*B1 + wk[5]*C1;
    s += wk[6]*A2 + wk[7]*B2 + wk[8]*C2c;

    float4 o;
    o.x = 0.5f*s[0]*(1.f + erff(s[0]*0.70710678118654752f));
    o.y = 0.5f*s[1]*(1.f + erff(s[1]*0.70710678118654752f));
    o.z = 0.5f*s[2]*(1.f + erff(s[2]*0.70710678118654752f));
    o.w = 0.5f*s[3]*(1.f + erff(s[3]*0.70710678118654752f));
    *(float4*)(gout + (size_t)ww*C2) = o;

    A0=B0; A1=B1; A2=B2;
    B0=C0; B1=C1; B2=C2c;
    C0=N0; C1=N1; C2c=N2;
  }
}

// ---------------- launch ----------------
extern "C" void kernel_launch(void* const* d_in, const int* in_sizes, int n_in,
                              void* d_out, int out_size, void* d_ws, size_t ws_size,
                              hipStream_t stream) {
  const float* x1     = (const float*)d_in[0];
  const float* x2     = (const float*)d_in[1];
  const float* ln1_g  = (const float*)d_in[2];
  const float* ln1_b  = (const float*)d_in[3];
  const float* qkv_w  = (const float*)d_in[4];
  const float* ca_temp= (const float*)d_in[5];
  const float* proj_w = (const float*)d_in[6];
  const float* proj_b = (const float*)d_in[7];
  const float* ln3_g  = (const float*)d_in[8];
  const float* ln3_b  = (const float*)d_in[9];
  const float* rp_w   = (const float*)d_in[10];
  const float* rp_b   = (const float*)d_in[11];
  const float* cn_g   = (const float*)d_in[12];
  const float* cn_b   = (const float*)d_in[13];
  const float* ln2_g  = (const float*)d_in[14];
  const float* ln2_b  = (const float*)d_in[15];
  const float* fc1_w  = (const float*)d_in[16];
  const float* fc1_b  = (const float*)d_in[17];
  const float* dw_w   = (const float*)d_in[18];
  const float* dw_b   = (const float*)d_in[19];
  const float* fc2_w  = (const float*)d_in[20];
  const float* fc2_b  = (const float*)d_in[21];
  float* out = (float*)d_out;
  float* W   = (float*)d_ws;

  // ---- workspace layout (peak 50,331,648 floats = 192 MiB) ----
  float* yco  = W;
  float* qkvb = W + (size_t)SZ_ND;
  float* ch1  = W + 25165824ull;
  float* ch2  = W + 31457280ull;
  unsigned short* qkvwT_h  = (unsigned short*)(W + 37748736ull);
  unsigned short* qkvwT_l  = qkvwT_h + 442368u;
  unsigned short* projwT_h = qkvwT_l + 442368u;
  unsigned short* projwT_l = projwT_h + 147456u;
  float* n1  = W;
  float* n2  = W + (size_t)SZ_ND;
  float* KS  = W + 2ull*SZ_ND;
  float* QS  = W + 3ull*SZ_ND;
  float* ctx = W + (size_t)SZ_ND;
  float* ATb = W;
  float* rep = W + (size_t)SZ_ND;
  unsigned short* rpw_h = (unsigned short*)(W + 37748736ull);
  unsigned short* rpw_l = rpw_h + 294912u;
  float* txp  = out;
  float* h1   = W;
  float* y2   = W + (size_t)SZ_NC2;
  float* gbuf = W + (size_t)SZ_NC2;
  unsigned short* fc1wT_h = (unsigned short*)(W + 37748736ull);
  unsigned short* fc1wT_l = fc1wT_h + 1179648u;
  unsigned short* fc2wT_h = (unsigned short*)W;
  unsigned short* fc2wT_l = fc2wT_h + 1179648u;

  const int M = BN*NN;

  // ---- phase-A weight prep ----
  wconv_t_kernel<<<dim3(1152/32, DD/32), dim3(256), 0, stream>>>(qkv_w, qkvwT_h, qkvwT_l, DD, 1152);
  wconv_t_kernel<<<dim3(DD/32, DD/32), dim3(256), 0, stream>>>(proj_w, projwT_h, projwT_l, DD, DD);

  // ---- channel attention, stream 1 ----
  ln_kernel<<<dim3(M), dim3(256), 0, stream>>>(x1, ln1_g, ln1_b, yco, DD);
  gemm_bf16x3_kernel<false,false><<<dim3(1152/128, M/128), dim3(256), 0, stream>>>(
      yco, qkvwT_h, qkvwT_l, nullptr, nullptr, qkvb, M, 1152, DD);
  chattn_mfma_kernel<<<dim3(BN*NHEAD), dim3(256), 0, stream>>>(qkvb, ca_temp, yco);
  gemm_bf16x3_kernel<true,true><<<dim3(DD/128, M/128), dim3(256), 0, stream>>>(
      yco, projwT_h, projwT_l, proj_b, x1, ch1, M, DD, DD);

  // ---- channel attention, stream 2 ----
  ln_kernel<<<dim3(M), dim3(256), 0, stream>>>(x2, ln1_g, ln1_b, yco, DD);
  gemm_bf16x3_kernel<false,false><<<dim3(1152/128, M/128), dim3(256), 0, stream>>>(
      yco, qkvwT_h, qkvwT_l, nullptr, nullptr, qkvb, M, 1152, DD);
  chattn_mfma_kernel<<<dim3(BN*NHEAD), dim3(256), 0, stream>>>(qkvb, ca_temp, yco);
  gemm_bf16x3_kernel<true,true><<<dim3(DD/128, M/128), dim3(256), 0, stream>>>(
      yco, projwT_h, projwT_l, proj_b, x2, ch2, M, DD, DD);

  // ---- cross attention ----
  wconv_kernel<<<dim3(294912/256), dim3(256), 0, stream>>>(rp_w, rpw_h, rpw_l, 294912);
  ln_kernel<<<dim3(M), dim3(256), 0, stream>>>(ch1, ln3_g, ln3_b, n1, DD);
  ln_kernel<<<dim3(M), dim3(256), 0, stream>>>(ch2, ln3_g, ln3_b, n2, DD);
  rowsoftmax_kernel<<<dim3(M), dim3(256), 0, stream>>>(n2, QS, DD);
  colsoftmax_kernel<<<dim3(DD/64, BN), dim3(256), 0, stream>>>(n2, KS);
  gemm64_kernel<true,false,false,false><<<dim3(DD/64, DD/64, BN), dim3(256), 0, stream>>>(
      KS, n1, nullptr, nullptr, ctx, DD, DD, NN,
      (size_t)NN*DD, (size_t)NN*DD, (size_t)DD*DD);
  gemm64_kernel<false,false,false,false><<<dim3(DD/64, NN/64, BN), dim3(256), 0, stream>>>(
      QS, ctx, nullptr, nullptr, ATb, NN, DD, DD,
      (size_t)NN*DD, (size_t)DD*DD, (size_t)NN*DD);
  gemm_bf16x3_kernel<true,false><<<dim3(D2/128, M/128), dim3(256), 0, stream>>>(
      ATb, rpw_h, rpw_l, rp_b, nullptr, rep, M, D2, DD);
  ln_concat_kernel<<<dim3(M), dim3(256), 0, stream>>>(rep, cn_g, cn_b, ch1, ch2, txp);

  // ---- mix FFN ----
  wconv_t_kernel<<<dim3(C2/32, D2/32), dim3(256), 0, stream>>>(fc1_w, fc1wT_h, fc1wT_l, D2, C2);
  ln_kernel<<<dim3(M), dim3(256), 0, stream>>>(txp, ln2_g, ln2_b, y2, D2);
  gemm_bf16x3_kernel<true,false><<<dim3(C2/128, M/128), dim3(256), 0, stream>>>(
      y2, fc1wT_h, fc1wT_l, fc1_b, nullptr, h1, M, C2, D2);
  dwconv_gelu_kernel<<<dim3(196608/256), dim3(256), 0, stream>>>(h1, dw_w, dw_b, gbuf);
  wconv_t_kernel<<<dim3(D2/32, C2/32), dim3(256), 0, stream>>>(fc2_w, fc2wT_h, fc2wT_l, C2, D2);
  gemm_bf16x3_kernel<true,true><<<dim3(D2/128, M/128), dim3(256), 0, stream>>>(
      gbuf, fc2wT_h, fc2wT_l, fc2_b, txp, out, M, D2, C2);
}